// Round 1
// baseline (288.463 us; speedup 1.0000x reference)
//
#include <hip/hip_runtime.h>

#define T_DIM 2000
#define N_DIM 128
#define IN_DIM 256
#define OUT_C 46
#define NROWS (T_DIM * N_DIM)
#define NCHUNK 125
#define CLEN 16
#define NSUPER 25
#define SLEN 5

// ---------------------------------------------------------------------------
// k1: y = x @ W^T + b.  Writes raw trans scores (cols 0..39) and final mod
// log-softmax values (cols 40..45) to out.  4 waves/block, 64 rows/block;
// each wave owns 11 output cols (wave-uniform -> scalar loads of W).
// ---------------------------------------------------------------------------
__global__ __launch_bounds__(256) void k1_gemm(const float* __restrict__ x,
                                               const float* __restrict__ W,
                                               const float* __restrict__ b,
                                               float* __restrict__ out) {
  const int lane = threadIdx.x & 63;
  const int wv   = threadIdx.x >> 6;
  const int row  = blockIdx.x * 64 + lane;
  const int c0   = __builtin_amdgcn_readfirstlane(wv * 11);

  float acc[11];
#pragma unroll
  for (int j = 0; j < 11; ++j) acc[j] = 0.f;

  const float* xr = x + (size_t)row * IN_DIM;
  for (int k = 0; k < IN_DIM; k += 4) {
    const float4 xv = *reinterpret_cast<const float4*>(xr + k);
#pragma unroll
    for (int j = 0; j < 11; ++j) {
      int c = c0 + j; c = c > 42 ? 42 : c;   // clamp (wave3 j=10 is a dummy)
      const float* wr = W + c * IN_DIM + k;  // wave-uniform -> s_load
      float a = acc[j];
      a = fmaf(xv.x, wr[0], a);
      a = fmaf(xv.y, wr[1], a);
      a = fmaf(xv.z, wr[2], a);
      a = fmaf(xv.w, wr[3], a);
      acc[j] = a;
    }
  }

  float yv[11];
#pragma unroll
  for (int j = 0; j < 11; ++j) {
    int c = c0 + j;
    yv[j] = acc[j] + (c < 43 ? b[c] : 0.f);
  }

  float* orow = out + (size_t)row * OUT_C;
#pragma unroll
  for (int j = 0; j < 11; ++j) {
    int c = c0 + j;
    if (c < 40) orow[c] = yv[j];
  }

  if (c0 == 33) {  // wave 3 holds y40,y41,y42 -> emit mod log-softmaxes
    float y40 = yv[7], y41 = yv[8], y42 = yv[9];
    float m01 = fmaxf(y40, y41);
    float l01 = m01 + log1pf(__expf(fminf(y40, y41) - m01));
    float m02 = fmaxf(y40, y42);
    float l02 = m02 + log1pf(__expf(fminf(y40, y42) - m02));
    orow[40] = y40 - l01;
    orow[41] = y41 - l01;
    orow[42] = y40 - l02;
    orow[43] = y42 - l02;
    orow[44] = 0.f;
    orow[45] = 0.f;
  }
}

// ---------------------------------------------------------------------------
// k2a: per (chunk c, column n), one lane builds the 8x8 linear-space product
// of 16 step matrices M_t (flip rows dense from exp(scores), flop rows
// 2-sparse), renormalizing every 4 steps and accumulating log-scale.
// ---------------------------------------------------------------------------
__global__ __launch_bounds__(64, 1) void k2a_chunk(const float* __restrict__ y,
                                                   float* __restrict__ wsM,
                                                   float* __restrict__ wsScale) {
  const int g  = blockIdx.x * 64 + threadIdx.x;
  const int c  = g >> 7;
  const int n  = g & 127;
  const int t0 = c * CLEN;
  const float* yb = y + (size_t)n * OUT_C;

  float M[8][8];
#pragma unroll
  for (int i = 0; i < 8; ++i)
#pragma unroll
    for (int j = 0; j < 8; ++j) M[i][j] = (i == j) ? 1.f : 0.f;
  float lsc = 0.f;
  float bufA[40], bufB[40];

#define LOADROW(BUF, TROW) do {                                              \
    const float* _yr = yb + (size_t)(TROW) * (N_DIM * OUT_C);                \
    _Pragma("unroll")                                                        \
    for (int _j = 0; _j < 20; ++_j) {                                        \
      float2 _v = *reinterpret_cast<const float2*>(_yr + 2 * _j);            \
      BUF[2 * _j] = _v.x; BUF[2 * _j + 1] = _v.y;                            \
    }                                                                        \
  } while (0)

#define STEPM(BUF) do {                                                      \
    float _e[40];                                                            \
    _Pragma("unroll")                                                        \
    for (int _q = 0; _q < 40; ++_q) _e[_q] = __expf(BUF[_q]);                \
    float _nm[8][8];                                                         \
    _Pragma("unroll")                                                        \
    for (int _j = 0; _j < 8; ++_j) {                                         \
      _Pragma("unroll")                                                      \
      for (int _i = 0; _i < 4; ++_i) {                                       \
        float _a = _e[8*_i+0]*M[0][_j] + _e[8*_i+1]*M[1][_j];                \
        float _b = _e[8*_i+2]*M[2][_j] + _e[8*_i+3]*M[3][_j];                \
        float _c = _e[8*_i+4]*M[4][_j] + _e[8*_i+5]*M[5][_j];                \
        float _d = _e[8*_i+6]*M[6][_j] + _e[8*_i+7]*M[7][_j];                \
        _nm[_i][_j] = (_a + _b) + (_c + _d);                                 \
      }                                                                      \
      _Pragma("unroll")                                                      \
      for (int _d2 = 0; _d2 < 4; ++_d2)                                      \
        _nm[4+_d2][_j] = _e[32+_d2]*M[_d2][_j] + _e[36+_d2]*M[4+_d2][_j];    \
    }                                                                        \
    _Pragma("unroll")                                                        \
    for (int _i = 0; _i < 8; ++_i)                                           \
      _Pragma("unroll")                                                      \
      for (int _j = 0; _j < 8; ++_j) M[_i][_j] = _nm[_i][_j];                \
  } while (0)

  LOADROW(bufA, t0);
  for (int s = 0; s < CLEN; s += 2) {
    LOADROW(bufB, t0 + s + 1);
    STEPM(bufA);
    if (s + 2 < CLEN) LOADROW(bufA, t0 + s + 2);
    STEPM(bufB);
    if ((s & 3) == 2) {  // after steps 3,7,11,15 -> final M is normalized
      float S = 0.f;
#pragma unroll
      for (int i = 0; i < 8; ++i)
#pragma unroll
        for (int j = 0; j < 8; ++j) S += M[i][j];
      lsc += __logf(S);
      const float inv = 1.0f / S;
#pragma unroll
      for (int i = 0; i < 8; ++i)
#pragma unroll
        for (int j = 0; j < 8; ++j) M[i][j] *= inv;
    }
  }
#undef LOADROW
#undef STEPM

  float* dst = wsM + (size_t)(c * N_DIM + n) * 64;
#pragma unroll
  for (int q = 0; q < 16; ++q) {
    float4 v;
    v.x = M[q >> 1][(q & 1) * 4 + 0];
    v.y = M[q >> 1][(q & 1) * 4 + 1];
    v.z = M[q >> 1][(q & 1) * 4 + 2];
    v.w = M[q >> 1][(q & 1) * 4 + 3];
    reinterpret_cast<float4*>(dst)[q] = v;
  }
  wsScale[c * N_DIM + n] = lsc;
}

// ---------------------------------------------------------------------------
// k2c: combine 5 consecutive chunk matrices into one super-matrix (dense 8x8
// matmuls), renormalizing each fold.
// ---------------------------------------------------------------------------
__global__ __launch_bounds__(64, 1) void k2c_super(const float* __restrict__ wsM,
                                                   const float* __restrict__ wsScale,
                                                   float* __restrict__ wsM2,
                                                   float* __restrict__ wsScale2) {
  const int g  = blockIdx.x * 64 + threadIdx.x;  // 0..3199
  const int sI = g >> 7;
  const int n  = g & 127;
  const int c0 = sI * SLEN;

  float A[8][8];
  {
    const float4* pa = reinterpret_cast<const float4*>(wsM + (size_t)(c0 * N_DIM + n) * 64);
#pragma unroll
    for (int q = 0; q < 16; ++q) {
      float4 v = pa[q];
      A[q >> 1][(q & 1) * 4 + 0] = v.x; A[q >> 1][(q & 1) * 4 + 1] = v.y;
      A[q >> 1][(q & 1) * 4 + 2] = v.z; A[q >> 1][(q & 1) * 4 + 3] = v.w;
    }
  }
  float lsc = wsScale[c0 * N_DIM + n];

#pragma unroll
  for (int u = 1; u < SLEN; ++u) {
    float B[8][8];
    const float4* pb = reinterpret_cast<const float4*>(wsM + (size_t)((c0 + u) * N_DIM + n) * 64);
#pragma unroll
    for (int q = 0; q < 16; ++q) {
      float4 v = pb[q];
      B[q >> 1][(q & 1) * 4 + 0] = v.x; B[q >> 1][(q & 1) * 4 + 1] = v.y;
      B[q >> 1][(q & 1) * 4 + 2] = v.z; B[q >> 1][(q & 1) * 4 + 3] = v.w;
    }
    lsc += wsScale[(c0 + u) * N_DIM + n];
    float C[8][8];
#pragma unroll
    for (int i = 0; i < 8; ++i) {
#pragma unroll
      for (int j = 0; j < 8; ++j) {
        float a0 = B[i][0] * A[0][j] + B[i][1] * A[1][j];
        float a1 = B[i][2] * A[2][j] + B[i][3] * A[3][j];
        float a2 = B[i][4] * A[4][j] + B[i][5] * A[5][j];
        float a3 = B[i][6] * A[6][j] + B[i][7] * A[7][j];
        C[i][j] = (a0 + a1) + (a2 + a3);
      }
    }
    float S = 0.f;
#pragma unroll
    for (int i = 0; i < 8; ++i)
#pragma unroll
      for (int j = 0; j < 8; ++j) S += C[i][j];
    lsc += __logf(S);
    const float inv = 1.0f / S;
#pragma unroll
    for (int i = 0; i < 8; ++i)
#pragma unroll
      for (int j = 0; j < 8; ++j) A[i][j] = C[i][j] * inv;
  }

  float* dst = wsM2 + (size_t)(sI * N_DIM + n) * 64;
#pragma unroll
  for (int q = 0; q < 16; ++q) {
    float4 v;
    v.x = A[q >> 1][(q & 1) * 4 + 0];
    v.y = A[q >> 1][(q & 1) * 4 + 1];
    v.z = A[q >> 1][(q & 1) * 4 + 2];
    v.w = A[q >> 1][(q & 1) * 4 + 3];
    reinterpret_cast<float4*>(dst)[q] = v;
  }
  wsScale2[sI * N_DIM + n] = lsc;
}

// ---------------------------------------------------------------------------
// k2b: fold p0 = [1,1,1,1,0,0,0,0] through the 25 super-matrices; one lane
// per column n.  logZ includes log(sum) of each fold + accumulated scales.
// ---------------------------------------------------------------------------
__global__ __launch_bounds__(128, 1) void k2b_fold(const float* __restrict__ wsM2,
                                                   const float* __restrict__ wsScale2,
                                                   float* __restrict__ wsLZ) {
  const int n = threadIdx.x;
  float p[8] = {1.f, 1.f, 1.f, 1.f, 0.f, 0.f, 0.f, 0.f};
  float lz = 0.f;
  for (int s2 = 0; s2 < NSUPER; ++s2) {
    const float4* Mp = reinterpret_cast<const float4*>(wsM2 + (size_t)(s2 * N_DIM + n) * 64);
    float np[8];
#pragma unroll
    for (int i = 0; i < 8; ++i) {
      float4 a = Mp[2 * i], c = Mp[2 * i + 1];
      float x0 = a.x * p[0] + a.y * p[1];
      float x1 = a.z * p[2] + a.w * p[3];
      float x2 = c.x * p[4] + c.y * p[5];
      float x3 = c.z * p[6] + c.w * p[7];
      np[i] = (x0 + x1) + (x2 + x3);
    }
    float S = ((np[0] + np[1]) + (np[2] + np[3])) + ((np[4] + np[5]) + (np[6] + np[7]));
    lz += __logf(S) + wsScale2[s2 * N_DIM + n];
    const float inv = 1.0f / S;
#pragma unroll
    for (int i = 0; i < 8; ++i) p[i] = np[i] * inv;
  }
  wsLZ[n] = lz * (1.0f / (float)T_DIM);
}

// ---------------------------------------------------------------------------
// k3: out[row, 0..39] -= logZ[n]/T  (mods cols 40..45 untouched)
// ---------------------------------------------------------------------------
__global__ __launch_bounds__(256) void k3_sub(float* __restrict__ out,
                                              const float* __restrict__ wsLZ) {
  const int row = blockIdx.x * 256 + threadIdx.x;
  if (row >= NROWS) return;
  const float sub = wsLZ[row & 127];
  float* o = out + (size_t)row * OUT_C;
#pragma unroll
  for (int j = 0; j < 20; ++j) {
    float2 v = *reinterpret_cast<float2*>(o + 2 * j);
    v.x -= sub; v.y -= sub;
    *reinterpret_cast<float2*>(o + 2 * j) = v;
  }
}

extern "C" void kernel_launch(void* const* d_in, const int* in_sizes, int n_in,
                              void* d_out, int out_size, void* d_ws, size_t ws_size,
                              hipStream_t stream) {
  (void)in_sizes; (void)n_in; (void)out_size; (void)ws_size;
  const float* x = (const float*)d_in[0];
  const float* W = (const float*)d_in[1];
  const float* b = (const float*)d_in[2];
  float* out = (float*)d_out;

  float* ws       = (float*)d_ws;
  float* wsM      = ws;                                  // 125*128*64 floats
  float* wsScale  = wsM + (size_t)NCHUNK * N_DIM * 64;   // 125*128
  float* wsM2     = wsScale + NCHUNK * N_DIM;            // 25*128*64
  float* wsScale2 = wsM2 + (size_t)NSUPER * N_DIM * 64;  // 25*128
  float* wsLZ     = wsScale2 + NSUPER * N_DIM;           // 128

  hipLaunchKernelGGL(k1_gemm,  dim3(NROWS / 64), dim3(256), 0, stream, x, W, b, out);
  hipLaunchKernelGGL(k2a_chunk, dim3(NCHUNK * N_DIM / 64), dim3(64), 0, stream, out, wsM, wsScale);
  hipLaunchKernelGGL(k2c_super, dim3(NSUPER * N_DIM / 64), dim3(64), 0, stream, wsM, wsScale, wsM2, wsScale2);
  hipLaunchKernelGGL(k2b_fold, dim3(1), dim3(128), 0, stream, wsM2, wsScale2, wsLZ);
  hipLaunchKernelGGL(k3_sub,   dim3((NROWS + 255) / 256), dim3(256), 0, stream, out, wsLZ);
}

// Round 2
// 274.714 us; speedup vs baseline: 1.0500x; 1.0500x over previous
//
#include <hip/hip_runtime.h>

#define T_DIM 2000
#define N_DIM 128
#define IN_DIM 256
#define OUT_C 46
#define NROWS (T_DIM * N_DIM)
#define NCHUNK 250
#define CLEN 8
#define NSUPER 25
#define SLEN 10

// ---------------------------------------------------------------------------
// k1: y = x @ W^T + b.  W staged in LDS (44 KB), broadcast ds_read_b128.
// Each thread owns 2 rows, all 43 columns in registers. Double-buffered x.
// ---------------------------------------------------------------------------
__global__ __launch_bounds__(256, 2) void k1_gemm(const float* __restrict__ x,
                                                  const float* __restrict__ W,
                                                  const float* __restrict__ b,
                                                  float* __restrict__ out) {
  __shared__ float Wl[43 * 256];
  const int tid = threadIdx.x;

  {  // stage W: 2752 float4s, coalesced
    const float4* Wg = reinterpret_cast<const float4*>(W);
    float4* Ws = reinterpret_cast<float4*>(Wl);
#pragma unroll
    for (int it = 0; it < 11; ++it) {
      int idx = tid + it * 256;
      if (idx < 2752) Ws[idx] = Wg[idx];
    }
  }
  __syncthreads();

  const int row0 = blockIdx.x * 512 + tid;
  const int row1 = row0 + 256;
  const float* xr0 = x + (size_t)row0 * IN_DIM;
  const float* xr1 = x + (size_t)row1 * IN_DIM;

  float acc0[43], acc1[43];
#pragma unroll
  for (int c = 0; c < 43; ++c) { acc0[c] = 0.f; acc1[c] = 0.f; }

  float4 a0 = *reinterpret_cast<const float4*>(xr0);
  float4 a1 = *reinterpret_cast<const float4*>(xr1);
  for (int k = 0; k < IN_DIM; k += 4) {
    float4 n0, n1;
    if (k + 4 < IN_DIM) {
      n0 = *reinterpret_cast<const float4*>(xr0 + k + 4);
      n1 = *reinterpret_cast<const float4*>(xr1 + k + 4);
    }
#pragma unroll
    for (int c = 0; c < 43; ++c) {
      const float4 w = *reinterpret_cast<const float4*>(&Wl[c * 256 + k]);
      float t0 = acc0[c], t1 = acc1[c];
      t0 = fmaf(a0.x, w.x, t0); t1 = fmaf(a1.x, w.x, t1);
      t0 = fmaf(a0.y, w.y, t0); t1 = fmaf(a1.y, w.y, t1);
      t0 = fmaf(a0.z, w.z, t0); t1 = fmaf(a1.z, w.z, t1);
      t0 = fmaf(a0.w, w.w, t0); t1 = fmaf(a1.w, w.w, t1);
      acc0[c] = t0; acc1[c] = t1;
    }
    a0 = n0; a1 = n1;
  }

#define EPILOG(ACC, ROWP) do {                                               \
    float y[43];                                                             \
    _Pragma("unroll") for (int c = 0; c < 43; ++c) y[c] = ACC[c] + b[c];     \
    float* o = (ROWP);                                                       \
    _Pragma("unroll") for (int q = 0; q < 20; ++q) {                         \
      float2 v; v.x = y[2*q]; v.y = y[2*q+1];                                \
      *reinterpret_cast<float2*>(o + 2*q) = v; }                             \
    float m01 = fmaxf(y[40], y[41]);                                         \
    float l01 = m01 + log1pf(__expf(fminf(y[40], y[41]) - m01));             \
    float m02 = fmaxf(y[40], y[42]);                                         \
    float l02 = m02 + log1pf(__expf(fminf(y[40], y[42]) - m02));             \
    float2 v0; v0.x = y[40] - l01; v0.y = y[41] - l01;                       \
    *reinterpret_cast<float2*>(o + 40) = v0;                                 \
    float2 v1; v1.x = y[40] - l02; v1.y = y[42] - l02;                       \
    *reinterpret_cast<float2*>(o + 42) = v1;                                 \
    float2 v2; v2.x = 0.f; v2.y = 0.f;                                       \
    *reinterpret_cast<float2*>(o + 44) = v2;                                 \
  } while (0)

  EPILOG(acc0, out + (size_t)row0 * OUT_C);
  EPILOG(acc1, out + (size_t)row1 * OUT_C);
#undef EPILOG
}

// ---------------------------------------------------------------------------
// k2a: per (chunk c, column n), one lane builds the 8x8 linear-space product
// of CLEN=8 step matrices (flip rows dense, flop rows 2-sparse), renorm
// every 4 steps with log-scale accumulation. Step 0 initializes M directly.
// ---------------------------------------------------------------------------
__global__ __launch_bounds__(256, 1) void k2a_chunk(const float* __restrict__ y,
                                                    float* __restrict__ wsM,
                                                    float* __restrict__ wsScale) {
  const int g  = blockIdx.x * 256 + threadIdx.x;
  const int c  = g >> 7;
  const int n  = g & 127;
  const int t0 = c * CLEN;
  const float* yb = y + (size_t)n * OUT_C;

  float M[8][8];
  float lsc = 0.f;
  float bufA[40], bufB[40];

#define LOADROW(BUF, TROW) do {                                              \
    const float* _yr = yb + (size_t)(TROW) * (N_DIM * OUT_C);                \
    _Pragma("unroll")                                                        \
    for (int _j = 0; _j < 20; ++_j) {                                        \
      float2 _v = *reinterpret_cast<const float2*>(_yr + 2 * _j);            \
      BUF[2 * _j] = _v.x; BUF[2 * _j + 1] = _v.y;                            \
    }                                                                        \
  } while (0)

#define INITM(BUF) do {                                                      \
    float _e[40];                                                            \
    _Pragma("unroll")                                                        \
    for (int _q = 0; _q < 40; ++_q) _e[_q] = __expf(BUF[_q]);                \
    _Pragma("unroll")                                                        \
    for (int _i = 0; _i < 4; ++_i)                                           \
      _Pragma("unroll")                                                      \
      for (int _j = 0; _j < 8; ++_j) M[_i][_j] = _e[8*_i+_j];                \
    _Pragma("unroll")                                                        \
    for (int _d = 0; _d < 4; ++_d) {                                         \
      _Pragma("unroll")                                                      \
      for (int _j = 0; _j < 8; ++_j) M[4+_d][_j] = 0.f;                      \
      M[4+_d][_d]   = _e[32+_d];                                             \
      M[4+_d][4+_d] = _e[36+_d];                                             \
    }                                                                        \
  } while (0)

#define STEPM(BUF) do {                                                      \
    float _e[40];                                                            \
    _Pragma("unroll")                                                        \
    for (int _q = 0; _q < 40; ++_q) _e[_q] = __expf(BUF[_q]);                \
    float _nm[8][8];                                                         \
    _Pragma("unroll")                                                        \
    for (int _j = 0; _j < 8; ++_j) {                                         \
      _Pragma("unroll")                                                      \
      for (int _i = 0; _i < 4; ++_i) {                                       \
        float _a = _e[8*_i+0]*M[0][_j] + _e[8*_i+1]*M[1][_j];                \
        float _b = _e[8*_i+2]*M[2][_j] + _e[8*_i+3]*M[3][_j];                \
        float _c = _e[8*_i+4]*M[4][_j] + _e[8*_i+5]*M[5][_j];                \
        float _d = _e[8*_i+6]*M[6][_j] + _e[8*_i+7]*M[7][_j];                \
        _nm[_i][_j] = (_a + _b) + (_c + _d);                                 \
      }                                                                      \
      _Pragma("unroll")                                                      \
      for (int _d2 = 0; _d2 < 4; ++_d2)                                      \
        _nm[4+_d2][_j] = _e[32+_d2]*M[_d2][_j] + _e[36+_d2]*M[4+_d2][_j];    \
    }                                                                        \
    _Pragma("unroll")                                                        \
    for (int _i = 0; _i < 8; ++_i)                                           \
      _Pragma("unroll")                                                      \
      for (int _j = 0; _j < 8; ++_j) M[_i][_j] = _nm[_i][_j];                \
  } while (0)

#define RENORM do {                                                          \
    float _S = 0.f;                                                          \
    _Pragma("unroll")                                                        \
    for (int _i = 0; _i < 8; ++_i)                                           \
      _Pragma("unroll")                                                      \
      for (int _j = 0; _j < 8; ++_j) _S += M[_i][_j];                        \
    lsc += __logf(_S);                                                       \
    const float _inv = 1.0f / _S;                                            \
    _Pragma("unroll")                                                        \
    for (int _i = 0; _i < 8; ++_i)                                           \
      _Pragma("unroll")                                                      \
      for (int _j = 0; _j < 8; ++_j) M[_i][_j] *= _inv;                      \
  } while (0)

  LOADROW(bufA, t0);
  LOADROW(bufB, t0 + 1);
  INITM(bufA);               // row 0
  LOADROW(bufA, t0 + 2);
  STEPM(bufB);               // row 1
  LOADROW(bufB, t0 + 3);
  STEPM(bufA);               // row 2
  LOADROW(bufA, t0 + 4);
  STEPM(bufB);               // row 3
  RENORM;
  LOADROW(bufB, t0 + 5);
  STEPM(bufA);               // row 4
  LOADROW(bufA, t0 + 6);
  STEPM(bufB);               // row 5
  LOADROW(bufB, t0 + 7);
  STEPM(bufA);               // row 6
  STEPM(bufB);               // row 7
  RENORM;

#undef LOADROW
#undef INITM
#undef STEPM
#undef RENORM

  float* dst = wsM + (size_t)(c * N_DIM + n) * 64;
#pragma unroll
  for (int q = 0; q < 16; ++q) {
    float4 v;
    v.x = M[q >> 1][(q & 1) * 4 + 0];
    v.y = M[q >> 1][(q & 1) * 4 + 1];
    v.z = M[q >> 1][(q & 1) * 4 + 2];
    v.w = M[q >> 1][(q & 1) * 4 + 3];
    reinterpret_cast<float4*>(dst)[q] = v;
  }
  wsScale[c * N_DIM + n] = lsc;
}

// ---------------------------------------------------------------------------
// k2c: fold SLEN=10 chunk matrices into one super-matrix, ping-pong prefetch.
// ---------------------------------------------------------------------------
__global__ __launch_bounds__(128, 1) void k2c_super(const float* __restrict__ wsM,
                                                    const float* __restrict__ wsScale,
                                                    float* __restrict__ wsM2,
                                                    float* __restrict__ wsScale2) {
  const int sI = blockIdx.x;     // 0..24
  const int n  = threadIdx.x;    // 0..127
  const int c0 = sI * SLEN;

  float A[8][8], B0[8][8], B1[8][8];
  float lsc = 0.f;
#pragma unroll
  for (int u = 0; u < SLEN; ++u) lsc += wsScale[(c0 + u) * N_DIM + n];

#define LOADM(DST, CIDX) do {                                                \
    const float4* _p = reinterpret_cast<const float4*>(                      \
        wsM + (size_t)((CIDX) * N_DIM + n) * 64);                            \
    _Pragma("unroll")                                                        \
    for (int _q = 0; _q < 16; ++_q) {                                        \
      float4 _v = _p[_q];                                                    \
      DST[_q >> 1][(_q & 1) * 4 + 0] = _v.x;                                 \
      DST[_q >> 1][(_q & 1) * 4 + 1] = _v.y;                                 \
      DST[_q >> 1][(_q & 1) * 4 + 2] = _v.z;                                 \
      DST[_q >> 1][(_q & 1) * 4 + 3] = _v.w;                                 \
    }                                                                        \
  } while (0)

#define FOLD(BB) do {                                                        \
    float C[8][8];                                                           \
    _Pragma("unroll")                                                        \
    for (int _i = 0; _i < 8; ++_i)                                           \
      _Pragma("unroll")                                                      \
      for (int _j = 0; _j < 8; ++_j) {                                       \
        float _a = BB[_i][0]*A[0][_j] + BB[_i][1]*A[1][_j];                  \
        float _b = BB[_i][2]*A[2][_j] + BB[_i][3]*A[3][_j];                  \
        float _c = BB[_i][4]*A[4][_j] + BB[_i][5]*A[5][_j];                  \
        float _d = BB[_i][6]*A[6][_j] + BB[_i][7]*A[7][_j];                  \
        C[_i][_j] = (_a + _b) + (_c + _d);                                   \
      }                                                                      \
    float _S = 0.f;                                                          \
    _Pragma("unroll")                                                        \
    for (int _i = 0; _i < 8; ++_i)                                           \
      _Pragma("unroll")                                                      \
      for (int _j = 0; _j < 8; ++_j) _S += C[_i][_j];                        \
    lsc += __logf(_S);                                                       \
    const float _inv = 1.0f / _S;                                            \
    _Pragma("unroll")                                                        \
    for (int _i = 0; _i < 8; ++_i)                                           \
      _Pragma("unroll")                                                      \
      for (int _j = 0; _j < 8; ++_j) A[_i][_j] = C[_i][_j] * _inv;           \
  } while (0)

  LOADM(A, c0);
  LOADM(B0, c0 + 1);
  LOADM(B1, c0 + 2);
  FOLD(B0); LOADM(B0, c0 + 3);
  FOLD(B1); LOADM(B1, c0 + 4);
  FOLD(B0); LOADM(B0, c0 + 5);
  FOLD(B1); LOADM(B1, c0 + 6);
  FOLD(B0); LOADM(B0, c0 + 7);
  FOLD(B1); LOADM(B1, c0 + 8);
  FOLD(B0); LOADM(B0, c0 + 9);
  FOLD(B1);
  FOLD(B0);
#undef LOADM
#undef FOLD

  float* dst = wsM2 + (size_t)(sI * N_DIM + n) * 64;
#pragma unroll
  for (int q = 0; q < 16; ++q) {
    float4 v;
    v.x = A[q >> 1][(q & 1) * 4 + 0];
    v.y = A[q >> 1][(q & 1) * 4 + 1];
    v.z = A[q >> 1][(q & 1) * 4 + 2];
    v.w = A[q >> 1][(q & 1) * 4 + 3];
    reinterpret_cast<float4*>(dst)[q] = v;
  }
  wsScale2[sI * N_DIM + n] = lsc;
}

// ---------------------------------------------------------------------------
// k2b: fold p0 through the 25 super-matrices. 8 lanes per column (one per
// state); all 25 matrices preloaded into registers; __shfl gathers p.
// ---------------------------------------------------------------------------
__global__ __launch_bounds__(128, 1) void k2b_fold(const float* __restrict__ wsM2,
                                                   const float* __restrict__ wsScale2,
                                                   float* __restrict__ wsLZ) {
  const int tid = threadIdx.x;
  const int n = blockIdx.x * 16 + (tid >> 3);
  const int i = tid & 7;
  const int gbase = (tid & 63) & ~7;

  float4 r0[NSUPER], r1[NSUPER];
  float sc[NSUPER];
#pragma unroll
  for (int s = 0; s < NSUPER; ++s) {
    const float* Mp = wsM2 + ((size_t)(s * N_DIM + n) * 64 + i * 8);
    r0[s] = *reinterpret_cast<const float4*>(Mp);
    r1[s] = *reinterpret_cast<const float4*>(Mp + 4);
    sc[s] = wsScale2[s * N_DIM + n];
  }

  float p[8] = {1.f, 1.f, 1.f, 1.f, 0.f, 0.f, 0.f, 0.f};
  float lz = 0.f;
#pragma unroll
  for (int s = 0; s < NSUPER; ++s) {
    float np = r0[s].x * p[0] + r0[s].y * p[1] + r0[s].z * p[2] + r0[s].w * p[3]
             + r1[s].x * p[4] + r1[s].y * p[5] + r1[s].z * p[6] + r1[s].w * p[7];
#pragma unroll
    for (int j = 0; j < 8; ++j) p[j] = __shfl(np, gbase + j, 64);
    float S = ((p[0] + p[1]) + (p[2] + p[3])) + ((p[4] + p[5]) + (p[6] + p[7]));
    lz += __logf(S) + sc[s];
    const float inv = 1.0f / S;
#pragma unroll
    for (int j = 0; j < 8; ++j) p[j] *= inv;
  }
  if (i == 0) wsLZ[n] = lz * (1.0f / (float)T_DIM);
}

// ---------------------------------------------------------------------------
// k3: out[row, 0..39] -= logZ[n]/T
// ---------------------------------------------------------------------------
__global__ __launch_bounds__(256) void k3_sub(float* __restrict__ out,
                                              const float* __restrict__ wsLZ) {
  const int row = blockIdx.x * 256 + threadIdx.x;
  if (row >= NROWS) return;
  const float sub = wsLZ[row & 127];
  float* o = out + (size_t)row * OUT_C;
#pragma unroll
  for (int j = 0; j < 20; ++j) {
    float2 v = *reinterpret_cast<float2*>(o + 2 * j);
    v.x -= sub; v.y -= sub;
    *reinterpret_cast<float2*>(o + 2 * j) = v;
  }
}

extern "C" void kernel_launch(void* const* d_in, const int* in_sizes, int n_in,
                              void* d_out, int out_size, void* d_ws, size_t ws_size,
                              hipStream_t stream) {
  (void)in_sizes; (void)n_in; (void)out_size; (void)ws_size;
  const float* x = (const float*)d_in[0];
  const float* W = (const float*)d_in[1];
  const float* b = (const float*)d_in[2];
  float* out = (float*)d_out;

  float* ws       = (float*)d_ws;
  float* wsM      = ws;                                  // 250*128*64 floats
  float* wsScale  = wsM + (size_t)NCHUNK * N_DIM * 64;   // 250*128
  float* wsM2     = wsScale + NCHUNK * N_DIM;            // 25*128*64
  float* wsScale2 = wsM2 + (size_t)NSUPER * N_DIM * 64;  // 25*128
  float* wsLZ     = wsScale2 + NSUPER * N_DIM;           // 128

  hipLaunchKernelGGL(k1_gemm,   dim3(NROWS / 512), dim3(256), 0, stream, x, W, b, out);
  hipLaunchKernelGGL(k2a_chunk, dim3(NCHUNK * N_DIM / 256), dim3(256), 0, stream, out, wsM, wsScale);
  hipLaunchKernelGGL(k2c_super, dim3(NSUPER), dim3(128), 0, stream, wsM, wsScale, wsM2, wsScale2);
  hipLaunchKernelGGL(k2b_fold,  dim3(8), dim3(128), 0, stream, wsM2, wsScale2, wsLZ);
  hipLaunchKernelGGL(k3_sub,    dim3((NROWS + 255) / 256), dim3(256), 0, stream, out, wsLZ);
}

// Round 3
// 200.811 us; speedup vs baseline: 1.4365x; 1.3680x over previous
//
#include <hip/hip_runtime.h>

#define T_DIM 2000
#define N_DIM 128
#define IN_DIM 256
#define OUT_C 46
#define NROWS (T_DIM * N_DIM)
#define NCHUNK 250
#define CLEN 8
#define NSUPER 25
#define SLEN 10

typedef float v2f __attribute__((ext_vector_type(2)));

__device__ __forceinline__ v2f lo2(float4 v) { v2f r; r.x = v.x; r.y = v.y; return r; }
__device__ __forceinline__ v2f hi2(float4 v) { v2f r; r.x = v.z; r.y = v.w; return r; }

// packed fp32 fma: acc.{x,y} += a.{x,y} * w.{x,y}
#define PKFMA(ACC, A, B) \
  asm("v_pk_fma_f32 %0, %1, %2, %0" : "+v"(ACC) : "v"(A), "v"(B))

// ---------------------------------------------------------------------------
// k1: y = x @ W^T + b.  W staged in LDS (44 KB), broadcast ds_read_b128.
// 2 rows/thread, k unrolled by 16 (64 B/lane per iter -> full cache-line use),
// packed-fp32 FMA with even/odd-k partial accumulators.
// ---------------------------------------------------------------------------
__global__ __launch_bounds__(256, 2) void k1_gemm(const float* __restrict__ x,
                                                  const float* __restrict__ W,
                                                  const float* __restrict__ b,
                                                  float* __restrict__ out) {
  __shared__ float4 Wl[43 * 64];  // [c][k/4]
  const int tid = threadIdx.x;

  {  // stage W: 2752 float4s, coalesced
    const float4* Wg = reinterpret_cast<const float4*>(W);
#pragma unroll
    for (int it = 0; it < 11; ++it) {
      int idx = tid + it * 256;
      if (idx < 2752) Wl[idx] = Wg[idx];
    }
  }
  __syncthreads();

  const int row0 = blockIdx.x * 512 + tid;
  const int row1 = row0 + 256;
  const float* xr0 = x + (size_t)row0 * IN_DIM;
  const float* xr1 = x + (size_t)row1 * IN_DIM;

  v2f acc0[43], acc1[43];
#pragma unroll
  for (int c = 0; c < 43; ++c) {
    acc0[c].x = 0.f; acc0[c].y = 0.f;
    acc1[c].x = 0.f; acc1[c].y = 0.f;
  }

  for (int k = 0; k < IN_DIM; k += 16) {
    float4 xa[4], xb[4];
#pragma unroll
    for (int q = 0; q < 4; ++q) {
      xa[q] = *reinterpret_cast<const float4*>(xr0 + k + 4 * q);
      xb[q] = *reinterpret_cast<const float4*>(xr1 + k + 4 * q);
    }
#pragma unroll
    for (int c = 0; c < 43; ++c) {
#pragma unroll
      for (int q = 0; q < 4; ++q) {
        const float4 w = Wl[c * 64 + (k >> 2) + q];
        const v2f wlo = lo2(w), whi = hi2(w);
        PKFMA(acc0[c], lo2(xa[q]), wlo);
        PKFMA(acc0[c], hi2(xa[q]), whi);
        PKFMA(acc1[c], lo2(xb[q]), wlo);
        PKFMA(acc1[c], hi2(xb[q]), whi);
      }
    }
  }

#define EPILOG(ACC, ROWP) do {                                               \
    float y[43];                                                             \
    _Pragma("unroll") for (int c = 0; c < 43; ++c)                           \
      y[c] = (ACC[c].x + ACC[c].y) + b[c];                                   \
    float* o = (ROWP);                                                       \
    _Pragma("unroll") for (int q = 0; q < 20; ++q) {                         \
      float2 v; v.x = y[2*q]; v.y = y[2*q+1];                                \
      *reinterpret_cast<float2*>(o + 2*q) = v; }                             \
    float m01 = fmaxf(y[40], y[41]);                                         \
    float l01 = m01 + log1pf(__expf(fminf(y[40], y[41]) - m01));             \
    float m02 = fmaxf(y[40], y[42]);                                         \
    float l02 = m02 + log1pf(__expf(fminf(y[40], y[42]) - m02));             \
    float2 v0; v0.x = y[40] - l01; v0.y = y[41] - l01;                       \
    *reinterpret_cast<float2*>(o + 40) = v0;                                 \
    float2 v1; v1.x = y[40] - l02; v1.y = y[42] - l02;                       \
    *reinterpret_cast<float2*>(o + 42) = v1;                                 \
    float2 v2; v2.x = 0.f; v2.y = 0.f;                                       \
    *reinterpret_cast<float2*>(o + 44) = v2;                                 \
  } while (0)

  EPILOG(acc0, out + (size_t)row0 * OUT_C);
  EPILOG(acc1, out + (size_t)row1 * OUT_C);
#undef EPILOG
}

// ---------------------------------------------------------------------------
// k2a: per (chunk c, column n), one lane builds the 8x8 linear-space product
// of CLEN=8 step matrices (flip rows dense, flop rows 2-sparse), renorm
// every 4 steps with log-scale accumulation. Step 0 initializes M directly.
// ---------------------------------------------------------------------------
__global__ __launch_bounds__(256, 1) void k2a_chunk(const float* __restrict__ y,
                                                    float* __restrict__ wsM,
                                                    float* __restrict__ wsScale) {
  const int g  = blockIdx.x * 256 + threadIdx.x;
  const int c  = g >> 7;
  const int n  = g & 127;
  const int t0 = c * CLEN;
  const float* yb = y + (size_t)n * OUT_C;

  float M[8][8];
  float lsc = 0.f;
  float bufA[40], bufB[40];

#define LOADROW(BUF, TROW) do {                                              \
    const float* _yr = yb + (size_t)(TROW) * (N_DIM * OUT_C);                \
    _Pragma("unroll")                                                        \
    for (int _j = 0; _j < 20; ++_j) {                                        \
      float2 _v = *reinterpret_cast<const float2*>(_yr + 2 * _j);            \
      BUF[2 * _j] = _v.x; BUF[2 * _j + 1] = _v.y;                            \
    }                                                                        \
  } while (0)

#define INITM(BUF) do {                                                      \
    float _e[40];                                                            \
    _Pragma("unroll")                                                        \
    for (int _q = 0; _q < 40; ++_q) _e[_q] = __expf(BUF[_q]);                \
    _Pragma("unroll")                                                        \
    for (int _i = 0; _i < 4; ++_i)                                           \
      _Pragma("unroll")                                                      \
      for (int _j = 0; _j < 8; ++_j) M[_i][_j] = _e[8*_i+_j];                \
    _Pragma("unroll")                                                        \
    for (int _d = 0; _d < 4; ++_d) {                                         \
      _Pragma("unroll")                                                      \
      for (int _j = 0; _j < 8; ++_j) M[4+_d][_j] = 0.f;                      \
      M[4+_d][_d]   = _e[32+_d];                                             \
      M[4+_d][4+_d] = _e[36+_d];                                             \
    }                                                                        \
  } while (0)

#define STEPM(BUF) do {                                                      \
    float _e[40];                                                            \
    _Pragma("unroll")                                                        \
    for (int _q = 0; _q < 40; ++_q) _e[_q] = __expf(BUF[_q]);                \
    float _nm[8][8];                                                         \
    _Pragma("unroll")                                                        \
    for (int _j = 0; _j < 8; ++_j) {                                         \
      _Pragma("unroll")                                                      \
      for (int _i = 0; _i < 4; ++_i) {                                       \
        float _a = _e[8*_i+0]*M[0][_j] + _e[8*_i+1]*M[1][_j];                \
        float _b = _e[8*_i+2]*M[2][_j] + _e[8*_i+3]*M[3][_j];                \
        float _c = _e[8*_i+4]*M[4][_j] + _e[8*_i+5]*M[5][_j];                \
        float _d = _e[8*_i+6]*M[6][_j] + _e[8*_i+7]*M[7][_j];                \
        _nm[_i][_j] = (_a + _b) + (_c + _d);                                 \
      }                                                                      \
      _Pragma("unroll")                                                      \
      for (int _d2 = 0; _d2 < 4; ++_d2)                                      \
        _nm[4+_d2][_j] = _e[32+_d2]*M[_d2][_j] + _e[36+_d2]*M[4+_d2][_j];    \
    }                                                                        \
    _Pragma("unroll")                                                        \
    for (int _i = 0; _i < 8; ++_i)                                           \
      _Pragma("unroll")                                                      \
      for (int _j = 0; _j < 8; ++_j) M[_i][_j] = _nm[_i][_j];                \
  } while (0)

#define RENORM do {                                                          \
    float _S = 0.f;                                                          \
    _Pragma("unroll")                                                        \
    for (int _i = 0; _i < 8; ++_i)                                           \
      _Pragma("unroll")                                                      \
      for (int _j = 0; _j < 8; ++_j) _S += M[_i][_j];                        \
    lsc += __logf(_S);                                                       \
    const float _inv = 1.0f / _S;                                            \
    _Pragma("unroll")                                                        \
    for (int _i = 0; _i < 8; ++_i)                                           \
      _Pragma("unroll")                                                      \
      for (int _j = 0; _j < 8; ++_j) M[_i][_j] *= _inv;                      \
  } while (0)

  LOADROW(bufA, t0);
  LOADROW(bufB, t0 + 1);
  INITM(bufA);               // row 0
  LOADROW(bufA, t0 + 2);
  STEPM(bufB);               // row 1
  LOADROW(bufB, t0 + 3);
  STEPM(bufA);               // row 2
  LOADROW(bufA, t0 + 4);
  STEPM(bufB);               // row 3
  RENORM;
  LOADROW(bufB, t0 + 5);
  STEPM(bufA);               // row 4
  LOADROW(bufA, t0 + 6);
  STEPM(bufB);               // row 5
  LOADROW(bufB, t0 + 7);
  STEPM(bufA);               // row 6
  STEPM(bufB);               // row 7
  RENORM;

#undef LOADROW
#undef INITM
#undef STEPM
#undef RENORM

  float* dst = wsM + (size_t)(c * N_DIM + n) * 64;
#pragma unroll
  for (int q = 0; q < 16; ++q) {
    float4 v;
    v.x = M[q >> 1][(q & 1) * 4 + 0];
    v.y = M[q >> 1][(q & 1) * 4 + 1];
    v.z = M[q >> 1][(q & 1) * 4 + 2];
    v.w = M[q >> 1][(q & 1) * 4 + 3];
    reinterpret_cast<float4*>(dst)[q] = v;
  }
  wsScale[c * N_DIM + n] = lsc;
}

// ---------------------------------------------------------------------------
// k2c: fold SLEN=10 chunk matrices into one super-matrix, ping-pong prefetch.
// ---------------------------------------------------------------------------
__global__ __launch_bounds__(128, 1) void k2c_super(const float* __restrict__ wsM,
                                                    const float* __restrict__ wsScale,
                                                    float* __restrict__ wsM2,
                                                    float* __restrict__ wsScale2) {
  const int sI = blockIdx.x;     // 0..24
  const int n  = threadIdx.x;    // 0..127
  const int c0 = sI * SLEN;

  float A[8][8], B0[8][8], B1[8][8];
  float lsc = 0.f;
#pragma unroll
  for (int u = 0; u < SLEN; ++u) lsc += wsScale[(c0 + u) * N_DIM + n];

#define LOADM(DST, CIDX) do {                                                \
    const float4* _p = reinterpret_cast<const float4*>(                      \
        wsM + (size_t)((CIDX) * N_DIM + n) * 64);                            \
    _Pragma("unroll")                                                        \
    for (int _q = 0; _q < 16; ++_q) {                                        \
      float4 _v = _p[_q];                                                    \
      DST[_q >> 1][(_q & 1) * 4 + 0] = _v.x;                                 \
      DST[_q >> 1][(_q & 1) * 4 + 1] = _v.y;                                 \
      DST[_q >> 1][(_q & 1) * 4 + 2] = _v.z;                                 \
      DST[_q >> 1][(_q & 1) * 4 + 3] = _v.w;                                 \
    }                                                                        \
  } while (0)

#define FOLD(BB) do {                                                        \
    float C[8][8];                                                           \
    _Pragma("unroll")                                                        \
    for (int _i = 0; _i < 8; ++_i)                                           \
      _Pragma("unroll")                                                      \
      for (int _j = 0; _j < 8; ++_j) {                                       \
        float _a = BB[_i][0]*A[0][_j] + BB[_i][1]*A[1][_j];                  \
        float _b = BB[_i][2]*A[2][_j] + BB[_i][3]*A[3][_j];                  \
        float _c = BB[_i][4]*A[4][_j] + BB[_i][5]*A[5][_j];                  \
        float _d = BB[_i][6]*A[6][_j] + BB[_i][7]*A[7][_j];                  \
        C[_i][_j] = (_a + _b) + (_c + _d);                                   \
      }                                                                      \
    float _S = 0.f;                                                          \
    _Pragma("unroll")                                                        \
    for (int _i = 0; _i < 8; ++_i)                                           \
      _Pragma("unroll")                                                      \
      for (int _j = 0; _j < 8; ++_j) _S += C[_i][_j];                        \
    lsc += __logf(_S);                                                       \
    const float _inv = 1.0f / _S;                                            \
    _Pragma("unroll")                                                        \
    for (int _i = 0; _i < 8; ++_i)                                           \
      _Pragma("unroll")                                                      \
      for (int _j = 0; _j < 8; ++_j) A[_i][_j] = C[_i][_j] * _inv;           \
  } while (0)

  LOADM(A, c0);
  LOADM(B0, c0 + 1);
  LOADM(B1, c0 + 2);
  FOLD(B0); LOADM(B0, c0 + 3);
  FOLD(B1); LOADM(B1, c0 + 4);
  FOLD(B0); LOADM(B0, c0 + 5);
  FOLD(B1); LOADM(B1, c0 + 6);
  FOLD(B0); LOADM(B0, c0 + 7);
  FOLD(B1); LOADM(B1, c0 + 8);
  FOLD(B0); LOADM(B0, c0 + 9);
  FOLD(B1);
  FOLD(B0);
#undef LOADM
#undef FOLD

  float* dst = wsM2 + (size_t)(sI * N_DIM + n) * 64;
#pragma unroll
  for (int q = 0; q < 16; ++q) {
    float4 v;
    v.x = A[q >> 1][(q & 1) * 4 + 0];
    v.y = A[q >> 1][(q & 1) * 4 + 1];
    v.z = A[q >> 1][(q & 1) * 4 + 2];
    v.w = A[q >> 1][(q & 1) * 4 + 3];
    reinterpret_cast<float4*>(dst)[q] = v;
  }
  wsScale2[sI * N_DIM + n] = lsc;
}

// ---------------------------------------------------------------------------
// k2b: fold p0 through the 25 super-matrices. 8 lanes per column (one per
// state); all 25 matrices preloaded into registers; __shfl gathers p.
// ---------------------------------------------------------------------------
__global__ __launch_bounds__(128, 1) void k2b_fold(const float* __restrict__ wsM2,
                                                   const float* __restrict__ wsScale2,
                                                   float* __restrict__ wsLZ) {
  const int tid = threadIdx.x;
  const int n = blockIdx.x * 16 + (tid >> 3);
  const int i = tid & 7;
  const int gbase = (tid & 63) & ~7;

  float4 r0[NSUPER], r1[NSUPER];
  float sc[NSUPER];
#pragma unroll
  for (int s = 0; s < NSUPER; ++s) {
    const float* Mp = wsM2 + ((size_t)(s * N_DIM + n) * 64 + i * 8);
    r0[s] = *reinterpret_cast<const float4*>(Mp);
    r1[s] = *reinterpret_cast<const float4*>(Mp + 4);
    sc[s] = wsScale2[s * N_DIM + n];
  }

  float p[8] = {1.f, 1.f, 1.f, 1.f, 0.f, 0.f, 0.f, 0.f};
  float lz = 0.f;
#pragma unroll
  for (int s = 0; s < NSUPER; ++s) {
    float np = r0[s].x * p[0] + r0[s].y * p[1] + r0[s].z * p[2] + r0[s].w * p[3]
             + r1[s].x * p[4] + r1[s].y * p[5] + r1[s].z * p[6] + r1[s].w * p[7];
#pragma unroll
    for (int j = 0; j < 8; ++j) p[j] = __shfl(np, gbase + j, 64);
    float S = ((p[0] + p[1]) + (p[2] + p[3])) + ((p[4] + p[5]) + (p[6] + p[7]));
    lz += __logf(S) + sc[s];
    const float inv = 1.0f / S;
#pragma unroll
    for (int j = 0; j < 8; ++j) p[j] *= inv;
  }
  if (i == 0) wsLZ[n] = lz * (1.0f / (float)T_DIM);
}

// ---------------------------------------------------------------------------
// k3: out[row, 0..39] -= logZ[n]/T
// ---------------------------------------------------------------------------
__global__ __launch_bounds__(256) void k3_sub(float* __restrict__ out,
                                              const float* __restrict__ wsLZ) {
  const int row = blockIdx.x * 256 + threadIdx.x;
  if (row >= NROWS) return;
  const float sub = wsLZ[row & 127];
  float* o = out + (size_t)row * OUT_C;
#pragma unroll
  for (int j = 0; j < 20; ++j) {
    float2 v = *reinterpret_cast<float2*>(o + 2 * j);
    v.x -= sub; v.y -= sub;
    *reinterpret_cast<float2*>(o + 2 * j) = v;
  }
}

extern "C" void kernel_launch(void* const* d_in, const int* in_sizes, int n_in,
                              void* d_out, int out_size, void* d_ws, size_t ws_size,
                              hipStream_t stream) {
  (void)in_sizes; (void)n_in; (void)out_size; (void)ws_size;
  const float* x = (const float*)d_in[0];
  const float* W = (const float*)d_in[1];
  const float* b = (const float*)d_in[2];
  float* out = (float*)d_out;

  float* ws       = (float*)d_ws;
  float* wsM      = ws;                                  // 250*128*64 floats
  float* wsScale  = wsM + (size_t)NCHUNK * N_DIM * 64;   // 250*128
  float* wsM2     = wsScale + NCHUNK * N_DIM;            // 25*128*64
  float* wsScale2 = wsM2 + (size_t)NSUPER * N_DIM * 64;  // 25*128
  float* wsLZ     = wsScale2 + NSUPER * N_DIM;           // 128

  hipLaunchKernelGGL(k1_gemm,   dim3(NROWS / 512), dim3(256), 0, stream, x, W, b, out);
  hipLaunchKernelGGL(k2a_chunk, dim3(NCHUNK * N_DIM / 256), dim3(256), 0, stream, out, wsM, wsScale);
  hipLaunchKernelGGL(k2c_super, dim3(NSUPER), dim3(128), 0, stream, wsM, wsScale, wsM2, wsScale2);
  hipLaunchKernelGGL(k2b_fold,  dim3(8), dim3(128), 0, stream, wsM2, wsScale2, wsLZ);
  hipLaunchKernelGGL(k3_sub,    dim3((NROWS + 255) / 256), dim3(256), 0, stream, out, wsLZ);
}

// Round 4
// 144.824 us; speedup vs baseline: 1.9918x; 1.3866x over previous
//
#include <hip/hip_runtime.h>

#define T_DIM 2000
#define N_DIM 128
#define IN_DIM 256
#define OUT_C 46
#define NROWS (T_DIM * N_DIM)
#define NCHUNK 250
#define CLEN 8
#define NSUPER 25
#define SLEN 10

typedef short bf16x8 __attribute__((ext_vector_type(8)));
typedef float f32x4 __attribute__((ext_vector_type(4)));

union F8U { bf16x8 v; uint32_t u[4]; };

__device__ __forceinline__ uint32_t cvtpk(float lo, float hi) {
  uint32_t r;
  asm("v_cvt_pk_bf16_f32 %0, %1, %2" : "=v"(r) : "v"(lo), "v"(hi));
  return r;
}

// ---------------------------------------------------------------------------
// k1: y = x @ W^T + b via MFMA 16x16x32 bf16. W (43x256) lives in VGPRs as
// B-fragments (loaded once per wave); A-fragments load straight from global
// in fragment layout (no LDS). Each wave: 4 tiles of 16 rows; block = 4
// waves = 256 rows. Writes RAW y to out cols 0..42 (mods finalized in k3).
// ---------------------------------------------------------------------------
__global__ __launch_bounds__(256, 2) void k1_gemm(const float* __restrict__ x,
                                                  const float* __restrict__ W,
                                                  const float* __restrict__ b,
                                                  float* __restrict__ out) {
  const int lane = threadIdx.x & 63;
  const int wv   = threadIdx.x >> 6;
  const int ln   = lane & 15;   // A-row / B-col / D-col index
  const int lh   = lane >> 4;   // k-group

  // --- B fragments: W[n][k], n = nt*16 + ln (clamped), k = s*32 + lh*8 + j ---
  F8U bfrag[3][8];
  float bias[3];
#pragma unroll
  for (int nt = 0; nt < 3; ++nt) {
    int n = nt * 16 + ln;
    if (n > 42) n = 42;                     // dup row 42 for pad cols (unused)
    bias[nt] = b[n];
    const float* wp = W + (size_t)n * IN_DIM + lh * 8;
#pragma unroll
    for (int s = 0; s < 8; ++s) {
      float4 w0 = *reinterpret_cast<const float4*>(wp + s * 32);
      float4 w1 = *reinterpret_cast<const float4*>(wp + s * 32 + 4);
      bfrag[nt][s].u[0] = cvtpk(w0.x, w0.y);
      bfrag[nt][s].u[1] = cvtpk(w0.z, w0.w);
      bfrag[nt][s].u[2] = cvtpk(w1.x, w1.y);
      bfrag[nt][s].u[3] = cvtpk(w1.z, w1.w);
    }
  }

  const int rowbase = blockIdx.x * 256 + wv * 64;
#pragma unroll 1
  for (int t = 0; t < 4; ++t) {
    const int trow = rowbase + t * 16;
    const float* xp = x + (size_t)(trow + ln) * IN_DIM + lh * 8;
    float4 xa[8], xb[8];
#pragma unroll
    for (int s = 0; s < 8; ++s) {
      xa[s] = *reinterpret_cast<const float4*>(xp + s * 32);
      xb[s] = *reinterpret_cast<const float4*>(xp + s * 32 + 4);
    }
    f32x4 zero = {0.f, 0.f, 0.f, 0.f};
    f32x4 acc[3] = {zero, zero, zero};
#pragma unroll
    for (int s = 0; s < 8; ++s) {
      F8U af;
      af.u[0] = cvtpk(xa[s].x, xa[s].y);
      af.u[1] = cvtpk(xa[s].z, xa[s].w);
      af.u[2] = cvtpk(xb[s].x, xb[s].y);
      af.u[3] = cvtpk(xb[s].z, xb[s].w);
#pragma unroll
      for (int nt = 0; nt < 3; ++nt)
        acc[nt] = __builtin_amdgcn_mfma_f32_16x16x32_bf16(af.v, bfrag[nt][s].v,
                                                          acc[nt], 0, 0, 0);
    }
    // D: col = ln (n), row = lh*4 + r (m)
    const int orow = trow + lh * 4;
#pragma unroll
    for (int nt = 0; nt < 3; ++nt) {
      const int col = nt * 16 + ln;
      if (nt < 2 || ln < 11) {
#pragma unroll
        for (int r = 0; r < 4; ++r)
          out[(size_t)(orow + r) * OUT_C + col] = acc[nt][r] + bias[nt];
      }
    }
  }
}

// ---------------------------------------------------------------------------
// k2a: per (chunk c, column n), one lane builds the 8x8 linear-space product
// of CLEN=8 step matrices (flip rows dense, flop rows 2-sparse), renorm
// every 4 steps with log-scale accumulation. Step 0 initializes M directly.
// ---------------------------------------------------------------------------
__global__ __launch_bounds__(256, 1) void k2a_chunk(const float* __restrict__ y,
                                                    float* __restrict__ wsM,
                                                    float* __restrict__ wsScale) {
  const int g  = blockIdx.x * 256 + threadIdx.x;
  const int c  = g >> 7;
  const int n  = g & 127;
  const int t0 = c * CLEN;
  const float* yb = y + (size_t)n * OUT_C;

  float M[8][8];
  float lsc = 0.f;
  float bufA[40], bufB[40];

#define LOADROW(BUF, TROW) do {                                              \
    const float* _yr = yb + (size_t)(TROW) * (N_DIM * OUT_C);                \
    _Pragma("unroll")                                                        \
    for (int _j = 0; _j < 20; ++_j) {                                        \
      float2 _v = *reinterpret_cast<const float2*>(_yr + 2 * _j);            \
      BUF[2 * _j] = _v.x; BUF[2 * _j + 1] = _v.y;                            \
    }                                                                        \
  } while (0)

#define INITM(BUF) do {                                                      \
    float _e[40];                                                            \
    _Pragma("unroll")                                                        \
    for (int _q = 0; _q < 40; ++_q) _e[_q] = __expf(BUF[_q]);                \
    _Pragma("unroll")                                                        \
    for (int _i = 0; _i < 4; ++_i)                                           \
      _Pragma("unroll")                                                      \
      for (int _j = 0; _j < 8; ++_j) M[_i][_j] = _e[8*_i+_j];                \
    _Pragma("unroll")                                                        \
    for (int _d = 0; _d < 4; ++_d) {                                         \
      _Pragma("unroll")                                                      \
      for (int _j = 0; _j < 8; ++_j) M[4+_d][_j] = 0.f;                      \
      M[4+_d][_d]   = _e[32+_d];                                             \
      M[4+_d][4+_d] = _e[36+_d];                                             \
    }                                                                        \
  } while (0)

#define STEPM(BUF) do {                                                      \
    float _e[40];                                                            \
    _Pragma("unroll")                                                        \
    for (int _q = 0; _q < 40; ++_q) _e[_q] = __expf(BUF[_q]);                \
    float _nm[8][8];                                                         \
    _Pragma("unroll")                                                        \
    for (int _j = 0; _j < 8; ++_j) {                                         \
      _Pragma("unroll")                                                      \
      for (int _i = 0; _i < 4; ++_i) {                                       \
        float _a = _e[8*_i+0]*M[0][_j] + _e[8*_i+1]*M[1][_j];                \
        float _b = _e[8*_i+2]*M[2][_j] + _e[8*_i+3]*M[3][_j];                \
        float _c = _e[8*_i+4]*M[4][_j] + _e[8*_i+5]*M[5][_j];                \
        float _d = _e[8*_i+6]*M[6][_j] + _e[8*_i+7]*M[7][_j];                \
        _nm[_i][_j] = (_a + _b) + (_c + _d);                                 \
      }                                                                      \
      _Pragma("unroll")                                                      \
      for (int _d2 = 0; _d2 < 4; ++_d2)                                      \
        _nm[4+_d2][_j] = _e[32+_d2]*M[_d2][_j] + _e[36+_d2]*M[4+_d2][_j];    \
    }                                                                        \
    _Pragma("unroll")                                                        \
    for (int _i = 0; _i < 8; ++_i)                                           \
      _Pragma("unroll")                                                      \
      for (int _j = 0; _j < 8; ++_j) M[_i][_j] = _nm[_i][_j];                \
  } while (0)

#define RENORM do {                                                          \
    float _S = 0.f;                                                          \
    _Pragma("unroll")                                                        \
    for (int _i = 0; _i < 8; ++_i)                                           \
      _Pragma("unroll")                                                      \
      for (int _j = 0; _j < 8; ++_j) _S += M[_i][_j];                        \
    lsc += __logf(_S);                                                       \
    const float _inv = 1.0f / _S;                                            \
    _Pragma("unroll")                                                        \
    for (int _i = 0; _i < 8; ++_i)                                           \
      _Pragma("unroll")                                                      \
      for (int _j = 0; _j < 8; ++_j) M[_i][_j] *= _inv;                      \
  } while (0)

  LOADROW(bufA, t0);
  LOADROW(bufB, t0 + 1);
  INITM(bufA);               // row 0
  LOADROW(bufA, t0 + 2);
  STEPM(bufB);               // row 1
  LOADROW(bufB, t0 + 3);
  STEPM(bufA);               // row 2
  LOADROW(bufA, t0 + 4);
  STEPM(bufB);               // row 3
  RENORM;
  LOADROW(bufB, t0 + 5);
  STEPM(bufA);               // row 4
  LOADROW(bufA, t0 + 6);
  STEPM(bufB);               // row 5
  LOADROW(bufB, t0 + 7);
  STEPM(bufA);               // row 6
  STEPM(bufB);               // row 7
  RENORM;

#undef LOADROW
#undef INITM
#undef STEPM
#undef RENORM

  float* dst = wsM + (size_t)(c * N_DIM + n) * 64;
#pragma unroll
  for (int q = 0; q < 16; ++q) {
    float4 v;
    v.x = M[q >> 1][(q & 1) * 4 + 0];
    v.y = M[q >> 1][(q & 1) * 4 + 1];
    v.z = M[q >> 1][(q & 1) * 4 + 2];
    v.w = M[q >> 1][(q & 1) * 4 + 3];
    reinterpret_cast<float4*>(dst)[q] = v;
  }
  wsScale[c * N_DIM + n] = lsc;
}

// ---------------------------------------------------------------------------
// k2c: fold SLEN=10 chunk matrices into one super-matrix, ping-pong prefetch.
// ---------------------------------------------------------------------------
__global__ __launch_bounds__(128, 1) void k2c_super(const float* __restrict__ wsM,
                                                    const float* __restrict__ wsScale,
                                                    float* __restrict__ wsM2,
                                                    float* __restrict__ wsScale2) {
  const int sI = blockIdx.x;     // 0..24
  const int n  = threadIdx.x;    // 0..127
  const int c0 = sI * SLEN;

  float A[8][8], B0[8][8], B1[8][8];
  float lsc = 0.f;
#pragma unroll
  for (int u = 0; u < SLEN; ++u) lsc += wsScale[(c0 + u) * N_DIM + n];

#define LOADM(DST, CIDX) do {                                                \
    const float4* _p = reinterpret_cast<const float4*>(                      \
        wsM + (size_t)((CIDX) * N_DIM + n) * 64);                            \
    _Pragma("unroll")                                                        \
    for (int _q = 0; _q < 16; ++_q) {                                        \
      float4 _v = _p[_q];                                                    \
      DST[_q >> 1][(_q & 1) * 4 + 0] = _v.x;                                 \
      DST[_q >> 1][(_q & 1) * 4 + 1] = _v.y;                                 \
      DST[_q >> 1][(_q & 1) * 4 + 2] = _v.z;                                 \
      DST[_q >> 1][(_q & 1) * 4 + 3] = _v.w;                                 \
    }                                                                        \
  } while (0)

#define FOLD(BB) do {                                                        \
    float C[8][8];                                                           \
    _Pragma("unroll")                                                        \
    for (int _i = 0; _i < 8; ++_i)                                           \
      _Pragma("unroll")                                                      \
      for (int _j = 0; _j < 8; ++_j) {                                       \
        float _a = BB[_i][0]*A[0][_j] + BB[_i][1]*A[1][_j];                  \
        float _b = BB[_i][2]*A[2][_j] + BB[_i][3]*A[3][_j];                  \
        float _c = BB[_i][4]*A[4][_j] + BB[_i][5]*A[5][_j];                  \
        float _d = BB[_i][6]*A[6][_j] + BB[_i][7]*A[7][_j];                  \
        C[_i][_j] = (_a + _b) + (_c + _d);                                   \
      }                                                                      \
    float _S = 0.f;                                                          \
    _Pragma("unroll")                                                        \
    for (int _i = 0; _i < 8; ++_i)                                           \
      _Pragma("unroll")                                                      \
      for (int _j = 0; _j < 8; ++_j) _S += C[_i][_j];                        \
    lsc += __logf(_S);                                                       \
    const float _inv = 1.0f / _S;                                            \
    _Pragma("unroll")                                                        \
    for (int _i = 0; _i < 8; ++_i)                                           \
      _Pragma("unroll")                                                      \
      for (int _j = 0; _j < 8; ++_j) A[_i][_j] = C[_i][_j] * _inv;           \
  } while (0)

  LOADM(A, c0);
  LOADM(B0, c0 + 1);
  LOADM(B1, c0 + 2);
  FOLD(B0); LOADM(B0, c0 + 3);
  FOLD(B1); LOADM(B1, c0 + 4);
  FOLD(B0); LOADM(B0, c0 + 5);
  FOLD(B1); LOADM(B1, c0 + 6);
  FOLD(B0); LOADM(B0, c0 + 7);
  FOLD(B1); LOADM(B1, c0 + 8);
  FOLD(B0); LOADM(B0, c0 + 9);
  FOLD(B1);
  FOLD(B0);
#undef LOADM
#undef FOLD

  float* dst = wsM2 + (size_t)(sI * N_DIM + n) * 64;
#pragma unroll
  for (int q = 0; q < 16; ++q) {
    float4 v;
    v.x = A[q >> 1][(q & 1) * 4 + 0];
    v.y = A[q >> 1][(q & 1) * 4 + 1];
    v.z = A[q >> 1][(q & 1) * 4 + 2];
    v.w = A[q >> 1][(q & 1) * 4 + 3];
    reinterpret_cast<float4*>(dst)[q] = v;
  }
  wsScale2[sI * N_DIM + n] = lsc;
}

// ---------------------------------------------------------------------------
// k2b: fold p0 through the 25 super-matrices. 8 lanes per column (one per
// state); all 25 matrices preloaded into registers; __shfl gathers p.
// ---------------------------------------------------------------------------
__global__ __launch_bounds__(128, 1) void k2b_fold(const float* __restrict__ wsM2,
                                                   const float* __restrict__ wsScale2,
                                                   float* __restrict__ wsLZ) {
  const int tid = threadIdx.x;
  const int n = blockIdx.x * 16 + (tid >> 3);
  const int i = tid & 7;
  const int gbase = (tid & 63) & ~7;

  float4 r0[NSUPER], r1[NSUPER];
  float sc[NSUPER];
#pragma unroll
  for (int s = 0; s < NSUPER; ++s) {
    const float* Mp = wsM2 + ((size_t)(s * N_DIM + n) * 64 + i * 8);
    r0[s] = *reinterpret_cast<const float4*>(Mp);
    r1[s] = *reinterpret_cast<const float4*>(Mp + 4);
    sc[s] = wsScale2[s * N_DIM + n];
  }

  float p[8] = {1.f, 1.f, 1.f, 1.f, 0.f, 0.f, 0.f, 0.f};
  float lz = 0.f;
#pragma unroll
  for (int s = 0; s < NSUPER; ++s) {
    float np = r0[s].x * p[0] + r0[s].y * p[1] + r0[s].z * p[2] + r0[s].w * p[3]
             + r1[s].x * p[4] + r1[s].y * p[5] + r1[s].z * p[6] + r1[s].w * p[7];
#pragma unroll
    for (int j = 0; j < 8; ++j) p[j] = __shfl(np, gbase + j, 64);
    float S = ((p[0] + p[1]) + (p[2] + p[3])) + ((p[4] + p[5]) + (p[6] + p[7]));
    lz += __logf(S) + sc[s];
    const float inv = 1.0f / S;
#pragma unroll
    for (int j = 0; j < 8; ++j) p[j] *= inv;
  }
  if (i == 0) wsLZ[n] = lz * (1.0f / (float)T_DIM);
}

// ---------------------------------------------------------------------------
// k3: out[row, 0..39] -= logZ[n]/T, and finalize mod log-softmax cols 40..45
// from the raw y40..y42 that k1 left in out.
// ---------------------------------------------------------------------------
__global__ __launch_bounds__(256) void k3_sub(float* __restrict__ out,
                                              const float* __restrict__ wsLZ) {
  const int row = blockIdx.x * 256 + threadIdx.x;
  if (row >= NROWS) return;
  const float sub = wsLZ[row & 127];
  float* o = out + (size_t)row * OUT_C;

  float2 vm = *reinterpret_cast<float2*>(o + 40);
  float y40 = vm.x, y41 = vm.y, y42 = o[42];

#pragma unroll
  for (int j = 0; j < 20; ++j) {
    float2 v = *reinterpret_cast<float2*>(o + 2 * j);
    v.x -= sub; v.y -= sub;
    *reinterpret_cast<float2*>(o + 2 * j) = v;
  }

  float m01 = fmaxf(y40, y41);
  float l01 = m01 + log1pf(__expf(fminf(y40, y41) - m01));
  float m02 = fmaxf(y40, y42);
  float l02 = m02 + log1pf(__expf(fminf(y40, y42) - m02));
  float2 v0; v0.x = y40 - l01; v0.y = y41 - l01;
  *reinterpret_cast<float2*>(o + 40) = v0;
  float2 v1; v1.x = y40 - l02; v1.y = y42 - l02;
  *reinterpret_cast<float2*>(o + 42) = v1;
  float2 v2; v2.x = 0.f; v2.y = 0.f;
  *reinterpret_cast<float2*>(o + 44) = v2;
}

extern "C" void kernel_launch(void* const* d_in, const int* in_sizes, int n_in,
                              void* d_out, int out_size, void* d_ws, size_t ws_size,
                              hipStream_t stream) {
  (void)in_sizes; (void)n_in; (void)out_size; (void)ws_size;
  const float* x = (const float*)d_in[0];
  const float* W = (const float*)d_in[1];
  const float* b = (const float*)d_in[2];
  float* out = (float*)d_out;

  float* ws       = (float*)d_ws;
  float* wsM      = ws;                                  // 250*128*64 floats
  float* wsScale  = wsM + (size_t)NCHUNK * N_DIM * 64;   // 250*128
  float* wsM2     = wsScale + NCHUNK * N_DIM;            // 25*128*64
  float* wsScale2 = wsM2 + (size_t)NSUPER * N_DIM * 64;  // 25*128
  float* wsLZ     = wsScale2 + NSUPER * N_DIM;           // 128

  hipLaunchKernelGGL(k1_gemm,   dim3(NROWS / 256), dim3(256), 0, stream, x, W, b, out);
  hipLaunchKernelGGL(k2a_chunk, dim3(NCHUNK * N_DIM / 256), dim3(256), 0, stream, out, wsM, wsScale);
  hipLaunchKernelGGL(k2c_super, dim3(NSUPER), dim3(128), 0, stream, wsM, wsScale, wsM2, wsScale2);
  hipLaunchKernelGGL(k2b_fold,  dim3(8), dim3(128), 0, stream, wsM2, wsScale2, wsLZ);
  hipLaunchKernelGGL(k3_sub,    dim3((NROWS + 255) / 256), dim3(256), 0, stream, out, wsLZ);
}

// Round 5
// 127.287 us; speedup vs baseline: 2.2662x; 1.1378x over previous
//
#include <hip/hip_runtime.h>

#define T_DIM 2000
#define N_DIM 128
#define IN_DIM 256
#define OUT_C 46
#define NROWS (T_DIM * N_DIM)
#define NCHUNK 250
#define CLEN 8
#define NSUPER 25
#define SLEN 10

typedef short bf16x8 __attribute__((ext_vector_type(8)));
typedef float f32x4 __attribute__((ext_vector_type(4)));

union F8U { bf16x8 v; uint32_t u[4]; };

__device__ __forceinline__ uint32_t cvtpk(float lo, float hi) {
  uint32_t r;
  asm("v_cvt_pk_bf16_f32 %0, %1, %2" : "=v"(r) : "v"(lo), "v"(hi));
  return r;
}

#define LDSK 264  // padded row length (shorts); 132 dwords == 4 mod 32 banks

// ---------------------------------------------------------------------------
// k1: y = x @ W^T + b via MFMA 16x16x32 bf16. W staged ONCE per block into
// LDS as bf16 with padded rows (conflict-free b128 reads); B-fragments come
// from LDS per k-step (3 ds_read_b128) instead of 96 resident VGPRs ->
// VGPR ~110 -> 4 waves/SIMD -> enough outstanding loads to pin HBM.
// A-fragments load straight from global in fragment layout.
// Writes RAW y to out cols 0..42 (mods finalized in k3).
// ---------------------------------------------------------------------------
__global__ __launch_bounds__(256, 4) void k1_gemm(const float* __restrict__ x,
                                                  const float* __restrict__ W,
                                                  const float* __restrict__ b,
                                                  float* __restrict__ out) {
  __shared__ unsigned short Wl[43 * LDSK];
  const int tid  = threadIdx.x;
  const int lane = tid & 63;
  const int wv   = tid >> 6;
  const int ln   = lane & 15;   // A-row / B-col / D-col index
  const int lh   = lane >> 4;   // k-group

  {  // stage W as bf16 into padded LDS rows: 5504 dword-pairs
    uint32_t* Wd = reinterpret_cast<uint32_t*>(Wl);
#pragma unroll
    for (int it = 0; it < 22; ++it) {
      int e = tid + it * 256;
      if (e < 43 * 128) {
        int n = e >> 7, kp = e & 127;
        float2 w = *reinterpret_cast<const float2*>(W + (size_t)n * IN_DIM + 2 * kp);
        Wd[n * (LDSK / 2) + kp] = cvtpk(w.x, w.y);
      }
    }
  }
  float bias[3];
#pragma unroll
  for (int nt = 0; nt < 3; ++nt) {
    int n = nt * 16 + ln;
    bias[nt] = b[n > 42 ? 42 : n];
  }
  __syncthreads();

  const int rowbase = blockIdx.x * 256 + wv * 64;
#pragma unroll 1
  for (int t = 0; t < 4; ++t) {
    const int trow = rowbase + t * 16;
    const float* xp = x + (size_t)(trow + ln) * IN_DIM + lh * 8;
    float4 xa[8], xb[8];
#pragma unroll
    for (int s = 0; s < 8; ++s) {
      xa[s] = *reinterpret_cast<const float4*>(xp + s * 32);
      xb[s] = *reinterpret_cast<const float4*>(xp + s * 32 + 4);
    }
    f32x4 zero = {0.f, 0.f, 0.f, 0.f};
    f32x4 acc[3] = {zero, zero, zero};
#pragma unroll
    for (int s = 0; s < 8; ++s) {
      F8U af;
      af.u[0] = cvtpk(xa[s].x, xa[s].y);
      af.u[1] = cvtpk(xa[s].z, xa[s].w);
      af.u[2] = cvtpk(xb[s].x, xb[s].y);
      af.u[3] = cvtpk(xb[s].z, xb[s].w);
#pragma unroll
      for (int nt = 0; nt < 3; ++nt) {
        const int n = nt * 16 + ln;
        const bf16x8 bf = *reinterpret_cast<const bf16x8*>(
            &Wl[n * LDSK + s * 32 + lh * 8]);
        acc[nt] = __builtin_amdgcn_mfma_f32_16x16x32_bf16(af.v, bf, acc[nt],
                                                          0, 0, 0);
      }
    }
    // D: col = ln (n), row = lh*4 + r (m)
    const int orow = trow + lh * 4;
#pragma unroll
    for (int nt = 0; nt < 3; ++nt) {
      const int col = nt * 16 + ln;
      if (nt < 2 || ln < 11) {
#pragma unroll
        for (int r = 0; r < 4; ++r)
          out[(size_t)(orow + r) * OUT_C + col] = acc[nt][r] + bias[nt];
      }
    }
  }
}

// ---------------------------------------------------------------------------
// k2a: per (chunk c, column n), one lane builds the 8x8 linear-space product
// of CLEN=8 step matrices (flip rows dense, flop rows 2-sparse), renorm
// every 4 steps with log-scale accumulation. Step 0 initializes M directly.
// ---------------------------------------------------------------------------
__global__ __launch_bounds__(256, 1) void k2a_chunk(const float* __restrict__ y,
                                                    float* __restrict__ wsM,
                                                    float* __restrict__ wsScale) {
  const int g  = blockIdx.x * 256 + threadIdx.x;
  const int c  = g >> 7;
  const int n  = g & 127;
  const int t0 = c * CLEN;
  const float* yb = y + (size_t)n * OUT_C;

  float M[8][8];
  float lsc = 0.f;
  float bufA[40], bufB[40];

#define LOADROW(BUF, TROW) do {                                              \
    const float* _yr = yb + (size_t)(TROW) * (N_DIM * OUT_C);                \
    _Pragma("unroll")                                                        \
    for (int _j = 0; _j < 20; ++_j) {                                        \
      float2 _v = *reinterpret_cast<const float2*>(_yr + 2 * _j);            \
      BUF[2 * _j] = _v.x; BUF[2 * _j + 1] = _v.y;                            \
    }                                                                        \
  } while (0)

#define INITM(BUF) do {                                                      \
    float _e[40];                                                            \
    _Pragma("unroll")                                                        \
    for (int _q = 0; _q < 40; ++_q) _e[_q] = __expf(BUF[_q]);                \
    _Pragma("unroll")                                                        \
    for (int _i = 0; _i < 4; ++_i)                                           \
      _Pragma("unroll")                                                      \
      for (int _j = 0; _j < 8; ++_j) M[_i][_j] = _e[8*_i+_j];                \
    _Pragma("unroll")                                                        \
    for (int _d = 0; _d < 4; ++_d) {                                         \
      _Pragma("unroll")                                                      \
      for (int _j = 0; _j < 8; ++_j) M[4+_d][_j] = 0.f;                      \
      M[4+_d][_d]   = _e[32+_d];                                             \
      M[4+_d][4+_d] = _e[36+_d];                                             \
    }                                                                        \
  } while (0)

#define STEPM(BUF) do {                                                      \
    float _e[40];                                                            \
    _Pragma("unroll")                                                        \
    for (int _q = 0; _q < 40; ++_q) _e[_q] = __expf(BUF[_q]);                \
    float _nm[8][8];                                                         \
    _Pragma("unroll")                                                        \
    for (int _j = 0; _j < 8; ++_j) {                                         \
      _Pragma("unroll")                                                      \
      for (int _i = 0; _i < 4; ++_i) {                                       \
        float _a = _e[8*_i+0]*M[0][_j] + _e[8*_i+1]*M[1][_j];                \
        float _b = _e[8*_i+2]*M[2][_j] + _e[8*_i+3]*M[3][_j];                \
        float _c = _e[8*_i+4]*M[4][_j] + _e[8*_i+5]*M[5][_j];                \
        float _d = _e[8*_i+6]*M[6][_j] + _e[8*_i+7]*M[7][_j];                \
        _nm[_i][_j] = (_a + _b) + (_c + _d);                                 \
      }                                                                      \
      _Pragma("unroll")                                                      \
      for (int _d2 = 0; _d2 < 4; ++_d2)                                      \
        _nm[4+_d2][_j] = _e[32+_d2]*M[_d2][_j] + _e[36+_d2]*M[4+_d2][_j];    \
    }                                                                        \
    _Pragma("unroll")                                                        \
    for (int _i = 0; _i < 8; ++_i)                                           \
      _Pragma("unroll")                                                      \
      for (int _j = 0; _j < 8; ++_j) M[_i][_j] = _nm[_i][_j];                \
  } while (0)

#define RENORM do {                                                          \
    float _S = 0.f;                                                          \
    _Pragma("unroll")                                                        \
    for (int _i = 0; _i < 8; ++_i)                                           \
      _Pragma("unroll")                                                      \
      for (int _j = 0; _j < 8; ++_j) _S += M[_i][_j];                        \
    lsc += __logf(_S);                                                       \
    const float _inv = 1.0f / _S;                                            \
    _Pragma("unroll")                                                        \
    for (int _i = 0; _i < 8; ++_i)                                           \
      _Pragma("unroll")                                                      \
      for (int _j = 0; _j < 8; ++_j) M[_i][_j] *= _inv;                      \
  } while (0)

  LOADROW(bufA, t0);
  LOADROW(bufB, t0 + 1);
  INITM(bufA);               // row 0
  LOADROW(bufA, t0 + 2);
  STEPM(bufB);               // row 1
  LOADROW(bufB, t0 + 3);
  STEPM(bufA);               // row 2
  LOADROW(bufA, t0 + 4);
  STEPM(bufB);               // row 3
  RENORM;
  LOADROW(bufB, t0 + 5);
  STEPM(bufA);               // row 4
  LOADROW(bufA, t0 + 6);
  STEPM(bufB);               // row 5
  LOADROW(bufB, t0 + 7);
  STEPM(bufA);               // row 6
  STEPM(bufB);               // row 7
  RENORM;

#undef LOADROW
#undef INITM
#undef STEPM
#undef RENORM

  float* dst = wsM + (size_t)(c * N_DIM + n) * 64;
#pragma unroll
  for (int q = 0; q < 16; ++q) {
    float4 v;
    v.x = M[q >> 1][(q & 1) * 4 + 0];
    v.y = M[q >> 1][(q & 1) * 4 + 1];
    v.z = M[q >> 1][(q & 1) * 4 + 2];
    v.w = M[q >> 1][(q & 1) * 4 + 3];
    reinterpret_cast<float4*>(dst)[q] = v;
  }
  wsScale[c * N_DIM + n] = lsc;
}

// ---------------------------------------------------------------------------
// k2c: fold SLEN=10 chunk matrices into one super-matrix, ping-pong prefetch.
// ---------------------------------------------------------------------------
__global__ __launch_bounds__(128, 1) void k2c_super(const float* __restrict__ wsM,
                                                    const float* __restrict__ wsScale,
                                                    float* __restrict__ wsM2,
                                                    float* __restrict__ wsScale2) {
  const int sI = blockIdx.x;     // 0..24
  const int n  = threadIdx.x;    // 0..127
  const int c0 = sI * SLEN;

  float A[8][8], B0[8][8], B1[8][8];
  float lsc = 0.f;
#pragma unroll
  for (int u = 0; u < SLEN; ++u) lsc += wsScale[(c0 + u) * N_DIM + n];

#define LOADM(DST, CIDX) do {                                                \
    const float4* _p = reinterpret_cast<const float4*>(                      \
        wsM + (size_t)((CIDX) * N_DIM + n) * 64);                            \
    _Pragma("unroll")                                                        \
    for (int _q = 0; _q < 16; ++_q) {                                        \
      float4 _v = _p[_q];                                                    \
      DST[_q >> 1][(_q & 1) * 4 + 0] = _v.x;                                 \
      DST[_q >> 1][(_q & 1) * 4 + 1] = _v.y;                                 \
      DST[_q >> 1][(_q & 1) * 4 + 2] = _v.z;                                 \
      DST[_q >> 1][(_q & 1) * 4 + 3] = _v.w;                                 \
    }                                                                        \
  } while (0)

#define FOLD(BB) do {                                                        \
    float C[8][8];                                                           \
    _Pragma("unroll")                                                        \
    for (int _i = 0; _i < 8; ++_i)                                           \
      _Pragma("unroll")                                                      \
      for (int _j = 0; _j < 8; ++_j) {                                       \
        float _a = BB[_i][0]*A[0][_j] + BB[_i][1]*A[1][_j];                  \
        float _b = BB[_i][2]*A[2][_j] + BB[_i][3]*A[3][_j];                  \
        float _c = BB[_i][4]*A[4][_j] + BB[_i][5]*A[5][_j];                  \
        float _d = BB[_i][6]*A[6][_j] + BB[_i][7]*A[7][_j];                  \
        C[_i][_j] = (_a + _b) + (_c + _d);                                   \
      }                                                                      \
    float _S = 0.f;                                                          \
    _Pragma("unroll")                                                        \
    for (int _i = 0; _i < 8; ++_i)                                           \
      _Pragma("unroll")                                                      \
      for (int _j = 0; _j < 8; ++_j) _S += C[_i][_j];                        \
    lsc += __logf(_S);                                                       \
    const float _inv = 1.0f / _S;                                            \
    _Pragma("unroll")                                                        \
    for (int _i = 0; _i < 8; ++_i)                                           \
      _Pragma("unroll")                                                      \
      for (int _j = 0; _j < 8; ++_j) A[_i][_j] = C[_i][_j] * _inv;           \
  } while (0)

  LOADM(A, c0);
  LOADM(B0, c0 + 1);
  LOADM(B1, c0 + 2);
  FOLD(B0); LOADM(B0, c0 + 3);
  FOLD(B1); LOADM(B1, c0 + 4);
  FOLD(B0); LOADM(B0, c0 + 5);
  FOLD(B1); LOADM(B1, c0 + 6);
  FOLD(B0); LOADM(B0, c0 + 7);
  FOLD(B1); LOADM(B1, c0 + 8);
  FOLD(B0); LOADM(B0, c0 + 9);
  FOLD(B1);
  FOLD(B0);
#undef LOADM
#undef FOLD

  float* dst = wsM2 + (size_t)(sI * N_DIM + n) * 64;
#pragma unroll
  for (int q = 0; q < 16; ++q) {
    float4 v;
    v.x = A[q >> 1][(q & 1) * 4 + 0];
    v.y = A[q >> 1][(q & 1) * 4 + 1];
    v.z = A[q >> 1][(q & 1) * 4 + 2];
    v.w = A[q >> 1][(q & 1) * 4 + 3];
    reinterpret_cast<float4*>(dst)[q] = v;
  }
  wsScale2[sI * N_DIM + n] = lsc;
}

// ---------------------------------------------------------------------------
// k2b: fold p0 through the 25 super-matrices. 8 lanes per column (one per
// state); all 25 matrices preloaded into registers; __shfl gathers p.
// ---------------------------------------------------------------------------
__global__ __launch_bounds__(128, 1) void k2b_fold(const float* __restrict__ wsM2,
                                                   const float* __restrict__ wsScale2,
                                                   float* __restrict__ wsLZ) {
  const int tid = threadIdx.x;
  const int n = blockIdx.x * 16 + (tid >> 3);
  const int i = tid & 7;
  const int gbase = (tid & 63) & ~7;

  float4 r0[NSUPER], r1[NSUPER];
  float sc[NSUPER];
#pragma unroll
  for (int s = 0; s < NSUPER; ++s) {
    const float* Mp = wsM2 + ((size_t)(s * N_DIM + n) * 64 + i * 8);
    r0[s] = *reinterpret_cast<const float4*>(Mp);
    r1[s] = *reinterpret_cast<const float4*>(Mp + 4);
    sc[s] = wsScale2[s * N_DIM + n];
  }

  float p[8] = {1.f, 1.f, 1.f, 1.f, 0.f, 0.f, 0.f, 0.f};
  float lz = 0.f;
#pragma unroll
  for (int s = 0; s < NSUPER; ++s) {
    float np = r0[s].x * p[0] + r0[s].y * p[1] + r0[s].z * p[2] + r0[s].w * p[3]
             + r1[s].x * p[4] + r1[s].y * p[5] + r1[s].z * p[6] + r1[s].w * p[7];
#pragma unroll
    for (int j = 0; j < 8; ++j) p[j] = __shfl(np, gbase + j, 64);
    float S = ((p[0] + p[1]) + (p[2] + p[3])) + ((p[4] + p[5]) + (p[6] + p[7]));
    lz += __logf(S) + sc[s];
    const float inv = 1.0f / S;
#pragma unroll
    for (int j = 0; j < 8; ++j) p[j] *= inv;
  }
  if (i == 0) wsLZ[n] = lz * (1.0f / (float)T_DIM);
}

// ---------------------------------------------------------------------------
// k3: out[row, 0..39] -= logZ[n]/T, and finalize mod log-softmax cols 40..45
// from the raw y40..y42 that k1 left in out.
// ---------------------------------------------------------------------------
__global__ __launch_bounds__(256) void k3_sub(float* __restrict__ out,
                                              const float* __restrict__ wsLZ) {
  const int row = blockIdx.x * 256 + threadIdx.x;
  if (row >= NROWS) return;
  const float sub = wsLZ[row & 127];
  float* o = out + (size_t)row * OUT_C;

  float2 vm = *reinterpret_cast<float2*>(o + 40);
  float y40 = vm.x, y41 = vm.y, y42 = o[42];

#pragma unroll
  for (int j = 0; j < 20; ++j) {
    float2 v = *reinterpret_cast<float2*>(o + 2 * j);
    v.x -= sub; v.y -= sub;
    *reinterpret_cast<float2*>(o + 2 * j) = v;
  }

  float m01 = fmaxf(y40, y41);
  float l01 = m01 + log1pf(__expf(fminf(y40, y41) - m01));
  float m02 = fmaxf(y40, y42);
  float l02 = m02 + log1pf(__expf(fminf(y40, y42) - m02));
  float2 v0; v0.x = y40 - l01; v0.y = y41 - l01;
  *reinterpret_cast<float2*>(o + 40) = v0;
  float2 v1; v1.x = y40 - l02; v1.y = y42 - l02;
  *reinterpret_cast<float2*>(o + 42) = v1;
  float2 v2; v2.x = 0.f; v2.y = 0.f;
  *reinterpret_cast<float2*>(o + 44) = v2;
}

extern "C" void kernel_launch(void* const* d_in, const int* in_sizes, int n_in,
                              void* d_out, int out_size, void* d_ws, size_t ws_size,
                              hipStream_t stream) {
  (void)in_sizes; (void)n_in; (void)out_size; (void)ws_size;
  const float* x = (const float*)d_in[0];
  const float* W = (const float*)d_in[1];
  const float* b = (const float*)d_in[2];
  float* out = (float*)d_out;

  float* ws       = (float*)d_ws;
  float* wsM      = ws;                                  // 250*128*64 floats
  float* wsScale  = wsM + (size_t)NCHUNK * N_DIM * 64;   // 250*128
  float* wsM2     = wsScale + NCHUNK * N_DIM;            // 25*128*64
  float* wsScale2 = wsM2 + (size_t)NSUPER * N_DIM * 64;  // 25*128
  float* wsLZ     = wsScale2 + NSUPER * N_DIM;           // 128

  hipLaunchKernelGGL(k1_gemm,   dim3(NROWS / 256), dim3(256), 0, stream, x, W, b, out);
  hipLaunchKernelGGL(k2a_chunk, dim3(NCHUNK * N_DIM / 256), dim3(256), 0, stream, out, wsM, wsScale);
  hipLaunchKernelGGL(k2c_super, dim3(NSUPER), dim3(128), 0, stream, wsM, wsScale, wsM2, wsScale2);
  hipLaunchKernelGGL(k2b_fold,  dim3(8), dim3(128), 0, stream, wsM2, wsScale2, wsLZ);
  hipLaunchKernelGGL(k3_sub,    dim3((NROWS + 255) / 256), dim3(256), 0, stream, out, wsLZ);
}

// Round 6
// 126.453 us; speedup vs baseline: 2.2812x; 1.0066x over previous
//
#include <hip/hip_runtime.h>

#define T_DIM 2000
#define N_DIM 128
#define IN_DIM 256
#define OUT_C 46
#define NROWS (T_DIM * N_DIM)
#define NCHUNK 250
#define CLEN 8
#define NSUPER 25
#define SLEN 10

typedef short bf16x8 __attribute__((ext_vector_type(8)));
typedef float f32x4 __attribute__((ext_vector_type(4)));

union F8U { bf16x8 v; uint32_t u[4]; };

__device__ __forceinline__ uint32_t cvtpk(float lo, float hi) {
  uint32_t r;
  asm("v_cvt_pk_bf16_f32 %0, %1, %2" : "=v"(r) : "v"(lo), "v"(hi));
  return r;
}

#define LDSK 264  // padded row length (shorts); 132 dwords == 4 mod 32 banks

// ---------------------------------------------------------------------------
// k1: y = x @ W^T + b via MFMA 16x16x32 bf16. W staged once per block into
// LDS as bf16 (padded rows, conflict-free b128). A-path is software-pipelined
// at HALF-TILE granularity: two 32-VGPR ping-pong buffers; loads for the next
// half-tile issue while the current half's cvt/ds_read/MFMA run, keeping
// 8-16 loads outstanding per wave continuously (fixes the load/compute phase
// serialization that left HBM idle). VGPR ~100 -> 4 waves/SIMD.
// Writes RAW y to out cols 0..42 (mods finalized in k3).
// ---------------------------------------------------------------------------
__global__ __launch_bounds__(256, 4) void k1_gemm(const float* __restrict__ x,
                                                  const float* __restrict__ W,
                                                  const float* __restrict__ b,
                                                  float* __restrict__ out) {
  __shared__ unsigned short Wl[43 * LDSK];
  const int tid  = threadIdx.x;
  const int lane = tid & 63;
  const int wv   = tid >> 6;
  const int ln   = lane & 15;   // A-row / B-col / D-col index
  const int lh   = lane >> 4;   // k-group

  {  // stage W as bf16 into padded LDS rows: 5504 dword-pairs
    uint32_t* Wd = reinterpret_cast<uint32_t*>(Wl);
#pragma unroll
    for (int it = 0; it < 22; ++it) {
      int e = tid + it * 256;
      if (e < 43 * 128) {
        int n = e >> 7, kp = e & 127;
        float2 w = *reinterpret_cast<const float2*>(W + (size_t)n * IN_DIM + 2 * kp);
        Wd[n * (LDSK / 2) + kp] = cvtpk(w.x, w.y);
      }
    }
  }
  float bias[3];
#pragma unroll
  for (int nt = 0; nt < 3; ++nt) {
    int n = nt * 16 + ln;
    bias[nt] = b[n > 42 ? 42 : n];
  }
  __syncthreads();

  const int rowbase = blockIdx.x * 256 + wv * 64;
  const float* xbase = x + (size_t)(rowbase + ln) * IN_DIM + lh * 8;

  float4 bufA[8], bufB[8];
  f32x4 zero = {0.f, 0.f, 0.f, 0.f};
  f32x4 acc[3] = {zero, zero, zero};

  // half-tile load: 8 x float4 (rows of tile T, k-range HF*128 .. +128)
#define LOADH(BUF, T, HF) do {                                               \
    const float* _p = xbase + (size_t)(T) * (16 * IN_DIM) + (HF) * 128;      \
    _Pragma("unroll")                                                        \
    for (int _s = 0; _s < 4; ++_s) {                                         \
      BUF[_s]     = *reinterpret_cast<const float4*>(_p + _s * 32);          \
      BUF[_s + 4] = *reinterpret_cast<const float4*>(_p + _s * 32 + 4);      \
    }                                                                        \
  } while (0)

  // half-tile compute: 16 cvt_pk, 12 ds_read_b128, 12 MFMA
#define COMPH(BUF, HF) do {                                                  \
    _Pragma("unroll")                                                        \
    for (int _s2 = 0; _s2 < 4; ++_s2) {                                      \
      F8U _af;                                                               \
      _af.u[0] = cvtpk(BUF[_s2].x, BUF[_s2].y);                              \
      _af.u[1] = cvtpk(BUF[_s2].z, BUF[_s2].w);                              \
      _af.u[2] = cvtpk(BUF[_s2 + 4].x, BUF[_s2 + 4].y);                      \
      _af.u[3] = cvtpk(BUF[_s2 + 4].z, BUF[_s2 + 4].w);                      \
      const int _s = (HF) * 4 + _s2;                                         \
      _Pragma("unroll")                                                      \
      for (int _nt = 0; _nt < 3; ++_nt) {                                    \
        const bf16x8 _bf = *reinterpret_cast<const bf16x8*>(                 \
            &Wl[(_nt * 16 + ln) * LDSK + _s * 32 + lh * 8]);                 \
        acc[_nt] = __builtin_amdgcn_mfma_f32_16x16x32_bf16(_af.v, _bf,       \
                                                           acc[_nt], 0, 0, 0);\
      }                                                                      \
    }                                                                        \
  } while (0)

  LOADH(bufA, 0, 0);
  LOADH(bufB, 0, 1);
#pragma unroll 1
  for (int t = 0; t < 4; ++t) {
    COMPH(bufA, 0);
    if (t < 3) LOADH(bufA, t + 1, 0);
    COMPH(bufB, 1);
    if (t < 3) LOADH(bufB, t + 1, 1);
    // epilogue for tile t: D col = ln, row = lh*4 + r
    const int orow = rowbase + t * 16 + lh * 4;
#pragma unroll
    for (int nt = 0; nt < 3; ++nt) {
      const int col = nt * 16 + ln;
      if (nt < 2 || ln < 11) {
#pragma unroll
        for (int r = 0; r < 4; ++r)
          out[(size_t)(orow + r) * OUT_C + col] = acc[nt][r] + bias[nt];
      }
      acc[nt] = zero;
    }
  }
#undef LOADH
#undef COMPH
}

// ---------------------------------------------------------------------------
// k2a: per (chunk c, column n), one lane builds the 8x8 linear-space product
// of CLEN=8 step matrices (flip rows dense, flop rows 2-sparse), renorm
// every 4 steps with log-scale accumulation. Step 0 initializes M directly.
// ---------------------------------------------------------------------------
__global__ __launch_bounds__(256, 1) void k2a_chunk(const float* __restrict__ y,
                                                    float* __restrict__ wsM,
                                                    float* __restrict__ wsScale) {
  const int g  = blockIdx.x * 256 + threadIdx.x;
  const int c  = g >> 7;
  const int n  = g & 127;
  const int t0 = c * CLEN;
  const float* yb = y + (size_t)n * OUT_C;

  float M[8][8];
  float lsc = 0.f;
  float bufA[40], bufB[40];

#define LOADROW(BUF, TROW) do {                                              \
    const float* _yr = yb + (size_t)(TROW) * (N_DIM * OUT_C);                \
    _Pragma("unroll")                                                        \
    for (int _j = 0; _j < 20; ++_j) {                                        \
      float2 _v = *reinterpret_cast<const float2*>(_yr + 2 * _j);            \
      BUF[2 * _j] = _v.x; BUF[2 * _j + 1] = _v.y;                            \
    }                                                                        \
  } while (0)

#define INITM(BUF) do {                                                      \
    float _e[40];                                                            \
    _Pragma("unroll")                                                        \
    for (int _q = 0; _q < 40; ++_q) _e[_q] = __expf(BUF[_q]);                \
    _Pragma("unroll")                                                        \
    for (int _i = 0; _i < 4; ++_i)                                           \
      _Pragma("unroll")                                                      \
      for (int _j = 0; _j < 8; ++_j) M[_i][_j] = _e[8*_i+_j];                \
    _Pragma("unroll")                                                        \
    for (int _d = 0; _d < 4; ++_d) {                                         \
      _Pragma("unroll")                                                      \
      for (int _j = 0; _j < 8; ++_j) M[4+_d][_j] = 0.f;                      \
      M[4+_d][_d]   = _e[32+_d];                                             \
      M[4+_d][4+_d] = _e[36+_d];                                             \
    }                                                                        \
  } while (0)

#define STEPM(BUF) do {                                                      \
    float _e[40];                                                            \
    _Pragma("unroll")                                                        \
    for (int _q = 0; _q < 40; ++_q) _e[_q] = __expf(BUF[_q]);                \
    float _nm[8][8];                                                         \
    _Pragma("unroll")                                                        \
    for (int _j = 0; _j < 8; ++_j) {                                         \
      _Pragma("unroll")                                                      \
      for (int _i = 0; _i < 4; ++_i) {                                       \
        float _a = _e[8*_i+0]*M[0][_j] + _e[8*_i+1]*M[1][_j];                \
        float _b = _e[8*_i+2]*M[2][_j] + _e[8*_i+3]*M[3][_j];                \
        float _c = _e[8*_i+4]*M[4][_j] + _e[8*_i+5]*M[5][_j];                \
        float _d = _e[8*_i+6]*M[6][_j] + _e[8*_i+7]*M[7][_j];                \
        _nm[_i][_j] = (_a + _b) + (_c + _d);                                 \
      }                                                                      \
      _Pragma("unroll")                                                      \
      for (int _d2 = 0; _d2 < 4; ++_d2)                                      \
        _nm[4+_d2][_j] = _e[32+_d2]*M[_d2][_j] + _e[36+_d2]*M[4+_d2][_j];    \
    }                                                                        \
    _Pragma("unroll")                                                        \
    for (int _i = 0; _i < 8; ++_i)                                           \
      _Pragma("unroll")                                                      \
      for (int _j = 0; _j < 8; ++_j) M[_i][_j] = _nm[_i][_j];                \
  } while (0)

#define RENORM do {                                                          \
    float _S = 0.f;                                                          \
    _Pragma("unroll")                                                        \
    for (int _i = 0; _i < 8; ++_i)                                           \
      _Pragma("unroll")                                                      \
      for (int _j = 0; _j < 8; ++_j) _S += M[_i][_j];                        \
    lsc += __logf(_S);                                                       \
    const float _inv = 1.0f / _S;                                            \
    _Pragma("unroll")                                                        \
    for (int _i = 0; _i < 8; ++_i)                                           \
      _Pragma("unroll")                                                      \
      for (int _j = 0; _j < 8; ++_j) M[_i][_j] *= _inv;                      \
  } while (0)

  LOADROW(bufA, t0);
  LOADROW(bufB, t0 + 1);
  INITM(bufA);               // row 0
  LOADROW(bufA, t0 + 2);
  STEPM(bufB);               // row 1
  LOADROW(bufB, t0 + 3);
  STEPM(bufA);               // row 2
  LOADROW(bufA, t0 + 4);
  STEPM(bufB);               // row 3
  RENORM;
  LOADROW(bufB, t0 + 5);
  STEPM(bufA);               // row 4
  LOADROW(bufA, t0 + 6);
  STEPM(bufB);               // row 5
  LOADROW(bufB, t0 + 7);
  STEPM(bufA);               // row 6
  STEPM(bufB);               // row 7
  RENORM;

#undef LOADROW
#undef INITM
#undef STEPM
#undef RENORM

  float* dst = wsM + (size_t)(c * N_DIM + n) * 64;
#pragma unroll
  for (int q = 0; q < 16; ++q) {
    float4 v;
    v.x = M[q >> 1][(q & 1) * 4 + 0];
    v.y = M[q >> 1][(q & 1) * 4 + 1];
    v.z = M[q >> 1][(q & 1) * 4 + 2];
    v.w = M[q >> 1][(q & 1) * 4 + 3];
    reinterpret_cast<float4*>(dst)[q] = v;
  }
  wsScale[c * N_DIM + n] = lsc;
}

// ---------------------------------------------------------------------------
// k2c: fold SLEN=10 chunk matrices into one super-matrix, ping-pong prefetch.
// ---------------------------------------------------------------------------
__global__ __launch_bounds__(128, 1) void k2c_super(const float* __restrict__ wsM,
                                                    const float* __restrict__ wsScale,
                                                    float* __restrict__ wsM2,
                                                    float* __restrict__ wsScale2) {
  const int sI = blockIdx.x;     // 0..24
  const int n  = threadIdx.x;    // 0..127
  const int c0 = sI * SLEN;

  float A[8][8], B0[8][8], B1[8][8];
  float lsc = 0.f;
#pragma unroll
  for (int u = 0; u < SLEN; ++u) lsc += wsScale[(c0 + u) * N_DIM + n];

#define LOADM(DST, CIDX) do {                                                \
    const float4* _p = reinterpret_cast<const float4*>(                      \
        wsM + (size_t)((CIDX) * N_DIM + n) * 64);                            \
    _Pragma("unroll")                                                        \
    for (int _q = 0; _q < 16; ++_q) {                                        \
      float4 _v = _p[_q];                                                    \
      DST[_q >> 1][(_q & 1) * 4 + 0] = _v.x;                                 \
      DST[_q >> 1][(_q & 1) * 4 + 1] = _v.y;                                 \
      DST[_q >> 1][(_q & 1) * 4 + 2] = _v.z;                                 \
      DST[_q >> 1][(_q & 1) * 4 + 3] = _v.w;                                 \
    }                                                                        \
  } while (0)

#define FOLD(BB) do {                                                        \
    float C[8][8];                                                           \
    _Pragma("unroll")                                                        \
    for (int _i = 0; _i < 8; ++_i)                                           \
      _Pragma("unroll")                                                      \
      for (int _j = 0; _j < 8; ++_j) {                                       \
        float _a = BB[_i][0]*A[0][_j] + BB[_i][1]*A[1][_j];                  \
        float _b = BB[_i][2]*A[2][_j] + BB[_i][3]*A[3][_j];                  \
        float _c = BB[_i][4]*A[4][_j] + BB[_i][5]*A[5][_j];                  \
        float _d = BB[_i][6]*A[6][_j] + BB[_i][7]*A[7][_j];                  \
        C[_i][_j] = (_a + _b) + (_c + _d);                                   \
      }                                                                      \
    float _S = 0.f;                                                          \
    _Pragma("unroll")                                                        \
    for (int _i = 0; _i < 8; ++_i)                                           \
      _Pragma("unroll")                                                      \
      for (int _j = 0; _j < 8; ++_j) _S += C[_i][_j];                        \
    lsc += __logf(_S);                                                       \
    const float _inv = 1.0f / _S;                                            \
    _Pragma("unroll")                                                        \
    for (int _i = 0; _i < 8; ++_i)                                           \
      _Pragma("unroll")                                                      \
      for (int _j = 0; _j < 8; ++_j) A[_i][_j] = C[_i][_j] * _inv;           \
  } while (0)

  LOADM(A, c0);
  LOADM(B0, c0 + 1);
  LOADM(B1, c0 + 2);
  FOLD(B0); LOADM(B0, c0 + 3);
  FOLD(B1); LOADM(B1, c0 + 4);
  FOLD(B0); LOADM(B0, c0 + 5);
  FOLD(B1); LOADM(B1, c0 + 6);
  FOLD(B0); LOADM(B0, c0 + 7);
  FOLD(B1); LOADM(B1, c0 + 8);
  FOLD(B0); LOADM(B0, c0 + 9);
  FOLD(B1);
  FOLD(B0);
#undef LOADM
#undef FOLD

  float* dst = wsM2 + (size_t)(sI * N_DIM + n) * 64;
#pragma unroll
  for (int q = 0; q < 16; ++q) {
    float4 v;
    v.x = A[q >> 1][(q & 1) * 4 + 0];
    v.y = A[q >> 1][(q & 1) * 4 + 1];
    v.z = A[q >> 1][(q & 1) * 4 + 2];
    v.w = A[q >> 1][(q & 1) * 4 + 3];
    reinterpret_cast<float4*>(dst)[q] = v;
  }
  wsScale2[sI * N_DIM + n] = lsc;
}

// ---------------------------------------------------------------------------
// k2b: fold p0 through the 25 super-matrices. 8 lanes per column (one per
// state); all 25 matrices preloaded into registers; __shfl gathers p.
// ---------------------------------------------------------------------------
__global__ __launch_bounds__(128, 1) void k2b_fold(const float* __restrict__ wsM2,
                                                   const float* __restrict__ wsScale2,
                                                   float* __restrict__ wsLZ) {
  const int tid = threadIdx.x;
  const int n = blockIdx.x * 16 + (tid >> 3);
  const int i = tid & 7;
  const int gbase = (tid & 63) & ~7;

  float4 r0[NSUPER], r1[NSUPER];
  float sc[NSUPER];
#pragma unroll
  for (int s = 0; s < NSUPER; ++s) {
    const float* Mp = wsM2 + ((size_t)(s * N_DIM + n) * 64 + i * 8);
    r0[s] = *reinterpret_cast<const float4*>(Mp);
    r1[s] = *reinterpret_cast<const float4*>(Mp + 4);
    sc[s] = wsScale2[s * N_DIM + n];
  }

  float p[8] = {1.f, 1.f, 1.f, 1.f, 0.f, 0.f, 0.f, 0.f};
  float lz = 0.f;
#pragma unroll
  for (int s = 0; s < NSUPER; ++s) {
    float np = r0[s].x * p[0] + r0[s].y * p[1] + r0[s].z * p[2] + r0[s].w * p[3]
             + r1[s].x * p[4] + r1[s].y * p[5] + r1[s].z * p[6] + r1[s].w * p[7];
#pragma unroll
    for (int j = 0; j < 8; ++j) p[j] = __shfl(np, gbase + j, 64);
    float S = ((p[0] + p[1]) + (p[2] + p[3])) + ((p[4] + p[5]) + (p[6] + p[7]));
    lz += __logf(S) + sc[s];
    const float inv = 1.0f / S;
#pragma unroll
    for (int j = 0; j < 8; ++j) p[j] *= inv;
  }
  if (i == 0) wsLZ[n] = lz * (1.0f / (float)T_DIM);
}

// ---------------------------------------------------------------------------
// k3: out[row, 0..39] -= logZ[n]/T, and finalize mod log-softmax cols 40..45
// from the raw y40..y42 that k1 left in out.
// ---------------------------------------------------------------------------
__global__ __launch_bounds__(256) void k3_sub(float* __restrict__ out,
                                              const float* __restrict__ wsLZ) {
  const int row = blockIdx.x * 256 + threadIdx.x;
  if (row >= NROWS) return;
  const float sub = wsLZ[row & 127];
  float* o = out + (size_t)row * OUT_C;

  float2 vm = *reinterpret_cast<float2*>(o + 40);
  float y40 = vm.x, y41 = vm.y, y42 = o[42];

#pragma unroll
  for (int j = 0; j < 20; ++j) {
    float2 v = *reinterpret_cast<float2*>(o + 2 * j);
    v.x -= sub; v.y -= sub;
    *reinterpret_cast<float2*>(o + 2 * j) = v;
  }

  float m01 = fmaxf(y40, y41);
  float l01 = m01 + log1pf(__expf(fminf(y40, y41) - m01));
  float m02 = fmaxf(y40, y42);
  float l02 = m02 + log1pf(__expf(fminf(y40, y42) - m02));
  float2 v0; v0.x = y40 - l01; v0.y = y41 - l01;
  *reinterpret_cast<float2*>(o + 40) = v0;
  float2 v1; v1.x = y40 - l02; v1.y = y42 - l02;
  *reinterpret_cast<float2*>(o + 42) = v1;
  float2 v2; v2.x = 0.f; v2.y = 0.f;
  *reinterpret_cast<float2*>(o + 44) = v2;
}

extern "C" void kernel_launch(void* const* d_in, const int* in_sizes, int n_in,
                              void* d_out, int out_size, void* d_ws, size_t ws_size,
                              hipStream_t stream) {
  (void)in_sizes; (void)n_in; (void)out_size; (void)ws_size;
  const float* x = (const float*)d_in[0];
  const float* W = (const float*)d_in[1];
  const float* b = (const float*)d_in[2];
  float* out = (float*)d_out;

  float* ws       = (float*)d_ws;
  float* wsM      = ws;                                  // 250*128*64 floats
  float* wsScale  = wsM + (size_t)NCHUNK * N_DIM * 64;   // 250*128
  float* wsM2     = wsScale + NCHUNK * N_DIM;            // 25*128*64
  float* wsScale2 = wsM2 + (size_t)NSUPER * N_DIM * 64;  // 25*128
  float* wsLZ     = wsScale2 + NSUPER * N_DIM;           // 128

  hipLaunchKernelGGL(k1_gemm,   dim3(NROWS / 256), dim3(256), 0, stream, x, W, b, out);
  hipLaunchKernelGGL(k2a_chunk, dim3(NCHUNK * N_DIM / 256), dim3(256), 0, stream, out, wsM, wsScale);
  hipLaunchKernelGGL(k2c_super, dim3(NSUPER), dim3(128), 0, stream, wsM, wsScale, wsM2, wsScale2);
  hipLaunchKernelGGL(k2b_fold,  dim3(8), dim3(128), 0, stream, wsM2, wsScale2, wsLZ);
  hipLaunchKernelGGL(k3_sub,    dim3((NROWS + 255) / 256), dim3(256), 0, stream, out, wsLZ);
}

// Round 7
// 116.060 us; speedup vs baseline: 2.4855x; 1.0895x over previous
//
#include <hip/hip_runtime.h>

#define T_DIM 2000
#define N_DIM 128
#define IN_DIM 256
#define OUT_C 46
#define NROWS (T_DIM * N_DIM)
#define NCHUNK 250
#define CLEN 8
#define NSUPER 25
#define SLEN 10

typedef short bf16x8 __attribute__((ext_vector_type(8)));
typedef float f32x4 __attribute__((ext_vector_type(4)));

union F8U { bf16x8 v; uint32_t u[4]; };

__device__ __forceinline__ uint32_t cvtpk(float lo, float hi) {
  uint32_t r;
  asm("v_cvt_pk_bf16_f32 %0, %1, %2" : "=v"(r) : "v"(lo), "v"(hi));
  return r;
}

__device__ __forceinline__ float bf2f(unsigned short u) {
  uint32_t w = (uint32_t)u << 16;
  return __builtin_bit_cast(float, w);
}

#define LDSK 264  // padded W row length (shorts); conflict-free b128

// ---------------------------------------------------------------------------
// k1: y = x @ W^T + b via MFMA 16x16x32 bf16 (W in LDS, half-tile ping-pong
// A prefetch).  Output: trans scores (c<40) go TRANSPOSED as bf16 to
// wsYT[t][c][n] (8B uint2 stores: the 4 acc regs are 4 consecutive n);
// mod scores y40..42 go fp32 to wsMod[t][m][n].  `out` is not touched here.
// ---------------------------------------------------------------------------
__global__ __launch_bounds__(256, 4) void k1_gemm(const float* __restrict__ x,
                                                  const float* __restrict__ W,
                                                  const float* __restrict__ b,
                                                  unsigned short* __restrict__ wsYT,
                                                  float* __restrict__ wsMod) {
  __shared__ unsigned short Wl[43 * LDSK];
  const int tid  = threadIdx.x;
  const int lane = tid & 63;
  const int wv   = tid >> 6;
  const int ln   = lane & 15;   // A-row(n) / B-col(c) index
  const int lh   = lane >> 4;   // k-group

  {  // stage W as bf16 into padded LDS rows
    uint32_t* Wd = reinterpret_cast<uint32_t*>(Wl);
#pragma unroll
    for (int it = 0; it < 22; ++it) {
      int e = tid + it * 256;
      if (e < 43 * 128) {
        int n = e >> 7, kp = e & 127;
        float2 w = *reinterpret_cast<const float2*>(W + (size_t)n * IN_DIM + 2 * kp);
        Wd[n * (LDSK / 2) + kp] = cvtpk(w.x, w.y);
      }
    }
  }
  float bias[3];
#pragma unroll
  for (int nt = 0; nt < 3; ++nt) {
    int n = nt * 16 + ln;
    bias[nt] = b[n > 42 ? 42 : n];
  }
  __syncthreads();

  const int rowbase = blockIdx.x * 256 + wv * 64;
  const float* xbase = x + (size_t)(rowbase + ln) * IN_DIM + lh * 8;

  float4 bufA[8], bufB[8];
  f32x4 zero = {0.f, 0.f, 0.f, 0.f};
  f32x4 acc[3] = {zero, zero, zero};

#define LOADH(BUF, T, HF) do {                                               \
    const float* _p = xbase + (size_t)(T) * (16 * IN_DIM) + (HF) * 128;      \
    _Pragma("unroll")                                                        \
    for (int _s = 0; _s < 4; ++_s) {                                         \
      BUF[_s]     = *reinterpret_cast<const float4*>(_p + _s * 32);          \
      BUF[_s + 4] = *reinterpret_cast<const float4*>(_p + _s * 32 + 4);      \
    }                                                                        \
  } while (0)

#define COMPH(BUF, HF) do {                                                  \
    _Pragma("unroll")                                                        \
    for (int _s2 = 0; _s2 < 4; ++_s2) {                                      \
      F8U _af;                                                               \
      _af.u[0] = cvtpk(BUF[_s2].x, BUF[_s2].y);                              \
      _af.u[1] = cvtpk(BUF[_s2].z, BUF[_s2].w);                              \
      _af.u[2] = cvtpk(BUF[_s2 + 4].x, BUF[_s2 + 4].y);                      \
      _af.u[3] = cvtpk(BUF[_s2 + 4].z, BUF[_s2 + 4].w);                      \
      const int _s = (HF) * 4 + _s2;                                         \
      _Pragma("unroll")                                                      \
      for (int _nt = 0; _nt < 3; ++_nt) {                                    \
        const bf16x8 _bf = *reinterpret_cast<const bf16x8*>(                 \
            &Wl[(_nt * 16 + ln) * LDSK + _s * 32 + lh * 8]);                 \
        acc[_nt] = __builtin_amdgcn_mfma_f32_16x16x32_bf16(_af.v, _bf,       \
                                                           acc[_nt], 0, 0, 0);\
      }                                                                      \
    }                                                                        \
  } while (0)

  LOADH(bufA, 0, 0);
  LOADH(bufB, 0, 1);
#pragma unroll 1
  for (int t = 0; t < 4; ++t) {
    COMPH(bufA, 0);
    if (t < 3) LOADH(bufA, t + 1, 0);
    COMPH(bufB, 1);
    if (t < 3) LOADH(bufB, t + 1, 1);
    // epilogue: tile base flat row R0; D reg r -> n = n0 + lh*4 + r, col = c
    const int R0 = rowbase + t * 16;
    const int tt = R0 >> 7;          // time index
    const int n0 = (R0 & 127) + lh * 4;
#pragma unroll
    for (int nt = 0; nt < 3; ++nt) {
      const int c = nt * 16 + ln;
      if (nt < 2 || ln < 8) {        // trans scores c<40 -> bf16 yT[t][c][n]
        uint32_t d0 = cvtpk(acc[nt][0] + bias[nt], acc[nt][1] + bias[nt]);
        uint32_t d1 = cvtpk(acc[nt][2] + bias[nt], acc[nt][3] + bias[nt]);
        uint2 v; v.x = d0; v.y = d1;
        *reinterpret_cast<uint2*>(wsYT + ((size_t)tt * 40 + c) * 128 + n0) = v;
      } else if (ln < 11) {          // c = 40..42 -> fp32 wsMod[t][c-40][n]
        float4 v;
        v.x = acc[2][0] + bias[2]; v.y = acc[2][1] + bias[2];
        v.z = acc[2][2] + bias[2]; v.w = acc[2][3] + bias[2];
        *reinterpret_cast<float4*>(
            wsMod + ((size_t)tt * 3 + (ln - 8)) * 128 + n0) = v;
      }
      acc[nt] = zero;
    }
  }
#undef LOADH
#undef COMPH
}

// ---------------------------------------------------------------------------
// k2a: per (chunk c, column n), one lane builds the 8x8 linear-space product
// of CLEN=8 step matrices.  Reads wsYT[t][q][n] as coalesced ushort loads
// (consecutive lanes = consecutive n -> 128B/instruction).
// ---------------------------------------------------------------------------
__global__ __launch_bounds__(256, 1) void k2a_chunk(const unsigned short* __restrict__ wsYT,
                                                    float* __restrict__ wsM,
                                                    float* __restrict__ wsScale) {
  const int g  = blockIdx.x * 256 + threadIdx.x;
  const int c  = g >> 7;
  const int n  = g & 127;
  const int t0 = c * CLEN;

  float M[8][8];
  float lsc = 0.f;
  float bufA[40], bufB[40];

#define LOADROW(BUF, TROW) do {                                              \
    const unsigned short* _yr = wsYT + (size_t)(TROW) * (40 * 128) + n;      \
    _Pragma("unroll")                                                        \
    for (int _q = 0; _q < 40; ++_q) BUF[_q] = bf2f(_yr[_q * 128]);           \
  } while (0)

#define INITM(BUF) do {                                                      \
    float _e[40];                                                            \
    _Pragma("unroll")                                                        \
    for (int _q = 0; _q < 40; ++_q) _e[_q] = __expf(BUF[_q]);                \
    _Pragma("unroll")                                                        \
    for (int _i = 0; _i < 4; ++_i)                                           \
      _Pragma("unroll")                                                      \
      for (int _j = 0; _j < 8; ++_j) M[_i][_j] = _e[8*_i+_j];                \
    _Pragma("unroll")                                                        \
    for (int _d = 0; _d < 4; ++_d) {                                         \
      _Pragma("unroll")                                                      \
      for (int _j = 0; _j < 8; ++_j) M[4+_d][_j] = 0.f;                      \
      M[4+_d][_d]   = _e[32+_d];                                             \
      M[4+_d][4+_d] = _e[36+_d];                                             \
    }                                                                        \
  } while (0)

#define STEPM(BUF) do {                                                      \
    float _e[40];                                                            \
    _Pragma("unroll")                                                        \
    for (int _q = 0; _q < 40; ++_q) _e[_q] = __expf(BUF[_q]);                \
    float _nm[8][8];                                                         \
    _Pragma("unroll")                                                        \
    for (int _j = 0; _j < 8; ++_j) {                                         \
      _Pragma("unroll")                                                      \
      for (int _i = 0; _i < 4; ++_i) {                                       \
        float _a = _e[8*_i+0]*M[0][_j] + _e[8*_i+1]*M[1][_j];                \
        float _b = _e[8*_i+2]*M[2][_j] + _e[8*_i+3]*M[3][_j];                \
        float _c = _e[8*_i+4]*M[4][_j] + _e[8*_i+5]*M[5][_j];                \
        float _d = _e[8*_i+6]*M[6][_j] + _e[8*_i+7]*M[7][_j];                \
        _nm[_i][_j] = (_a + _b) + (_c + _d);                                 \
      }                                                                      \
      _Pragma("unroll")                                                      \
      for (int _d2 = 0; _d2 < 4; ++_d2)                                      \
        _nm[4+_d2][_j] = _e[32+_d2]*M[_d2][_j] + _e[36+_d2]*M[4+_d2][_j];    \
    }                                                                        \
    _Pragma("unroll")                                                        \
    for (int _i = 0; _i < 8; ++_i)                                           \
      _Pragma("unroll")                                                      \
      for (int _j = 0; _j < 8; ++_j) M[_i][_j] = _nm[_i][_j];                \
  } while (0)

#define RENORM do {                                                          \
    float _S = 0.f;                                                          \
    _Pragma("unroll")                                                        \
    for (int _i = 0; _i < 8; ++_i)                                           \
      _Pragma("unroll")                                                      \
      for (int _j = 0; _j < 8; ++_j) _S += M[_i][_j];                        \
    lsc += __logf(_S);                                                       \
    const float _inv = 1.0f / _S;                                            \
    _Pragma("unroll")                                                        \
    for (int _i = 0; _i < 8; ++_i)                                           \
      _Pragma("unroll")                                                      \
      for (int _j = 0; _j < 8; ++_j) M[_i][_j] *= _inv;                      \
  } while (0)

  LOADROW(bufA, t0);
  LOADROW(bufB, t0 + 1);
  INITM(bufA);               // row 0
  LOADROW(bufA, t0 + 2);
  STEPM(bufB);               // row 1
  LOADROW(bufB, t0 + 3);
  STEPM(bufA);               // row 2
  LOADROW(bufA, t0 + 4);
  STEPM(bufB);               // row 3
  RENORM;
  LOADROW(bufB, t0 + 5);
  STEPM(bufA);               // row 4
  LOADROW(bufA, t0 + 6);
  STEPM(bufB);               // row 5
  LOADROW(bufB, t0 + 7);
  STEPM(bufA);               // row 6
  STEPM(bufB);               // row 7
  RENORM;

#undef LOADROW
#undef INITM
#undef STEPM
#undef RENORM

  float* dst = wsM + (size_t)(c * N_DIM + n) * 64;
#pragma unroll
  for (int q = 0; q < 16; ++q) {
    float4 v;
    v.x = M[q >> 1][(q & 1) * 4 + 0];
    v.y = M[q >> 1][(q & 1) * 4 + 1];
    v.z = M[q >> 1][(q & 1) * 4 + 2];
    v.w = M[q >> 1][(q & 1) * 4 + 3];
    reinterpret_cast<float4*>(dst)[q] = v;
  }
  wsScale[c * N_DIM + n] = lsc;
}

// ---------------------------------------------------------------------------
// k2c: fold SLEN=10 chunk matrices into one super-matrix, ping-pong prefetch.
// ---------------------------------------------------------------------------
__global__ __launch_bounds__(128, 1) void k2c_super(const float* __restrict__ wsM,
                                                    const float* __restrict__ wsScale,
                                                    float* __restrict__ wsM2,
                                                    float* __restrict__ wsScale2) {
  const int sI = blockIdx.x;     // 0..24
  const int n  = threadIdx.x;    // 0..127
  const int c0 = sI * SLEN;

  float A[8][8], B0[8][8], B1[8][8];
  float lsc = 0.f;
#pragma unroll
  for (int u = 0; u < SLEN; ++u) lsc += wsScale[(c0 + u) * N_DIM + n];

#define LOADM(DST, CIDX) do {                                                \
    const float4* _p = reinterpret_cast<const float4*>(                      \
        wsM + (size_t)((CIDX) * N_DIM + n) * 64);                            \
    _Pragma("unroll")                                                        \
    for (int _q = 0; _q < 16; ++_q) {                                        \
      float4 _v = _p[_q];                                                    \
      DST[_q >> 1][(_q & 1) * 4 + 0] = _v.x;                                 \
      DST[_q >> 1][(_q & 1) * 4 + 1] = _v.y;                                 \
      DST[_q >> 1][(_q & 1) * 4 + 2] = _v.z;                                 \
      DST[_q >> 1][(_q & 1) * 4 + 3] = _v.w;                                 \
    }                                                                        \
  } while (0)

#define FOLD(BB) do {                                                        \
    float C[8][8];                                                           \
    _Pragma("unroll")                                                        \
    for (int _i = 0; _i < 8; ++_i)                                           \
      _Pragma("unroll")                                                      \
      for (int _j = 0; _j < 8; ++_j) {                                       \
        float _a = BB[_i][0]*A[0][_j] + BB[_i][1]*A[1][_j];                  \
        float _b = BB[_i][2]*A[2][_j] + BB[_i][3]*A[3][_j];                  \
        float _c = BB[_i][4]*A[4][_j] + BB[_i][5]*A[5][_j];                  \
        float _d = BB[_i][6]*A[6][_j] + BB[_i][7]*A[7][_j];                  \
        C[_i][_j] = (_a + _b) + (_c + _d);                                   \
      }                                                                      \
    float _S = 0.f;                                                          \
    _Pragma("unroll")                                                        \
    for (int _i = 0; _i < 8; ++_i)                                           \
      _Pragma("unroll")                                                      \
      for (int _j = 0; _j < 8; ++_j) _S += C[_i][_j];                        \
    lsc += __logf(_S);                                                       \
    const float _inv = 1.0f / _S;                                            \
    _Pragma("unroll")                                                        \
    for (int _i = 0; _i < 8; ++_i)                                           \
      _Pragma("unroll")                                                      \
      for (int _j = 0; _j < 8; ++_j) A[_i][_j] = C[_i][_j] * _inv;           \
  } while (0)

  LOADM(A, c0);
  LOADM(B0, c0 + 1);
  LOADM(B1, c0 + 2);
  FOLD(B0); LOADM(B0, c0 + 3);
  FOLD(B1); LOADM(B1, c0 + 4);
  FOLD(B0); LOADM(B0, c0 + 5);
  FOLD(B1); LOADM(B1, c0 + 6);
  FOLD(B0); LOADM(B0, c0 + 7);
  FOLD(B1); LOADM(B1, c0 + 8);
  FOLD(B0); LOADM(B0, c0 + 9);
  FOLD(B1);
  FOLD(B0);
#undef LOADM
#undef FOLD

  float* dst = wsM2 + (size_t)(sI * N_DIM + n) * 64;
#pragma unroll
  for (int q = 0; q < 16; ++q) {
    float4 v;
    v.x = A[q >> 1][(q & 1) * 4 + 0];
    v.y = A[q >> 1][(q & 1) * 4 + 1];
    v.z = A[q >> 1][(q & 1) * 4 + 2];
    v.w = A[q >> 1][(q & 1) * 4 + 3];
    reinterpret_cast<float4*>(dst)[q] = v;
  }
  wsScale2[sI * N_DIM + n] = lsc;
}

// ---------------------------------------------------------------------------
// k2b: fold p0 through the 25 super-matrices. 8 lanes per column n.
// ---------------------------------------------------------------------------
__global__ __launch_bounds__(128, 1) void k2b_fold(const float* __restrict__ wsM2,
                                                   const float* __restrict__ wsScale2,
                                                   float* __restrict__ wsLZ) {
  const int tid = threadIdx.x;
  const int n = blockIdx.x * 16 + (tid >> 3);
  const int i = tid & 7;
  const int gbase = (tid & 63) & ~7;

  float4 r0[NSUPER], r1[NSUPER];
  float sc[NSUPER];
#pragma unroll
  for (int s = 0; s < NSUPER; ++s) {
    const float* Mp = wsM2 + ((size_t)(s * N_DIM + n) * 64 + i * 8);
    r0[s] = *reinterpret_cast<const float4*>(Mp);
    r1[s] = *reinterpret_cast<const float4*>(Mp + 4);
    sc[s] = wsScale2[s * N_DIM + n];
  }

  float p[8] = {1.f, 1.f, 1.f, 1.f, 0.f, 0.f, 0.f, 0.f};
  float lz = 0.f;
#pragma unroll
  for (int s = 0; s < NSUPER; ++s) {
    float np = r0[s].x * p[0] + r0[s].y * p[1] + r0[s].z * p[2] + r0[s].w * p[3]
             + r1[s].x * p[4] + r1[s].y * p[5] + r1[s].z * p[6] + r1[s].w * p[7];
#pragma unroll
    for (int j = 0; j < 8; ++j) p[j] = __shfl(np, gbase + j, 64);
    float S = ((p[0] + p[1]) + (p[2] + p[3])) + ((p[4] + p[5]) + (p[6] + p[7]));
    lz += __logf(S) + sc[s];
    const float inv = 1.0f / S;
#pragma unroll
    for (int j = 0; j < 8; ++j) p[j] *= inv;
  }
  if (i == 0) wsLZ[n] = lz * (1.0f / (float)T_DIM);
}

// ---------------------------------------------------------------------------
// k3: write the WHOLE output.  Block = 256 rows (2 t x 128 n).  Each thread
// builds its row (trans - logZ/T, mod log-softmaxes, zeros) in padded LDS;
// then a flat, fully-coalesced LDS -> global copy.  All global reads are
// lane-coalesced (consecutive lanes = consecutive n).  No RMW.
// ---------------------------------------------------------------------------
__global__ __launch_bounds__(256, 3) void k3_out(const unsigned short* __restrict__ wsYT,
                                                 const float* __restrict__ wsMod,
                                                 const float* __restrict__ wsLZ,
                                                 float* __restrict__ out) {
  __shared__ float L[256 * 47];
  const int tid = threadIdx.x;
  const int fr  = blockIdx.x * 256 + tid;
  const int t   = fr >> 7;
  const int n   = fr & 127;
  const float sub = wsLZ[n];

  const unsigned short* yr = wsYT + (size_t)t * (40 * 128) + n;
  float* lrow = &L[tid * 47];
#pragma unroll
  for (int c = 0; c < 40; ++c) lrow[c] = bf2f(yr[c * 128]) - sub;

  const float* mp = wsMod + (size_t)t * (3 * 128) + n;
  const float y40 = mp[0], y41 = mp[128], y42 = mp[256];
  const float m01 = fmaxf(y40, y41);
  const float l01 = m01 + log1pf(__expf(fminf(y40, y41) - m01));
  const float m02 = fmaxf(y40, y42);
  const float l02 = m02 + log1pf(__expf(fminf(y40, y42) - m02));
  lrow[40] = y40 - l01;
  lrow[41] = y41 - l01;
  lrow[42] = y40 - l02;
  lrow[43] = y42 - l02;
  lrow[44] = 0.f;
  lrow[45] = 0.f;
  __syncthreads();

  const size_t base = (size_t)blockIdx.x * (256 * 46);
#pragma unroll
  for (int j = 0; j < 46; ++j) {
    const int e = j * 256 + tid;
    const int r = e / 46;           // const-divisor -> magic-mul
    const int c = e - r * 46;
    out[base + e] = L[r * 47 + c];
  }
}

extern "C" void kernel_launch(void* const* d_in, const int* in_sizes, int n_in,
                              void* d_out, int out_size, void* d_ws, size_t ws_size,
                              hipStream_t stream) {
  (void)in_sizes; (void)n_in; (void)out_size; (void)ws_size;
  const float* x = (const float*)d_in[0];
  const float* W = (const float*)d_in[1];
  const float* b = (const float*)d_in[2];
  float* out = (float*)d_out;

  char* wsb = (char*)d_ws;
  unsigned short* wsYT = (unsigned short*)wsb;               // 2000*40*128 bf16
  float* wsMod   = (float*)(wsb + (size_t)T_DIM * 40 * 128 * 2);   // 2000*3*128 f32
  float* wsM     = wsMod + (size_t)T_DIM * 3 * N_DIM;        // 250*128*64
  float* wsScale = wsM + (size_t)NCHUNK * N_DIM * 64;        // 250*128
  float* wsM2    = wsScale + NCHUNK * N_DIM;                 // 25*128*64
  float* wsScale2= wsM2 + (size_t)NSUPER * N_DIM * 64;       // 25*128
  float* wsLZ    = wsScale2 + NSUPER * N_DIM;                // 128

  hipLaunchKernelGGL(k1_gemm,   dim3(NROWS / 256), dim3(256), 0, stream,
                     x, W, b, wsYT, wsMod);
  hipLaunchKernelGGL(k2a_chunk, dim3(NCHUNK * N_DIM / 256), dim3(256), 0, stream,
                     wsYT, wsM, wsScale);
  hipLaunchKernelGGL(k2c_super, dim3(NSUPER), dim3(128), 0, stream,
                     wsM, wsScale, wsM2, wsScale2);
  hipLaunchKernelGGL(k2b_fold,  dim3(8), dim3(128), 0, stream,
                     wsM2, wsScale2, wsLZ);
  hipLaunchKernelGGL(k3_out,    dim3(NROWS / 256), dim3(256), 0, stream,
                     wsYT, wsMod, wsLZ, out);
}